// Round 7
// baseline (2094.473 us; speedup 1.0000x reference)
//
#include <hip/hip_runtime.h>
#include <hip/hip_bf16.h>

#define NB 128
typedef __hip_bfloat16 bf;

__device__ __forceinline__ float relu_(float x){ return fmaxf(x, 0.f); }
__device__ __forceinline__ float B2F(bf v){ return __bfloat162float(v); }
__device__ __forceinline__ bf F2B(float v){ return __float2bfloat16(v); }

// transpose w[O][CK] -> wT[CK][O]
__global__ void transpose_w(const float* __restrict__ src, float* __restrict__ dst, int O, int CK) {
    int t = blockIdx.x*blockDim.x + threadIdx.x;
    if (t >= O*CK) return;
    int o = t / CK, ck = t - o*CK;
    dst[ck*O + o] = src[t];
}

// conv1: x[NB,1,256,256] fp32 -> bf16 [NB,8,128,128], 3x3 s2 p1, relu. 4 px/thread
__global__ void conv1_k(const float* __restrict__ x, const float* __restrict__ wT,
                        const float* __restrict__ b, bf* __restrict__ out) {
    __shared__ float sw[72];
    __shared__ float sb[8];
    if (threadIdx.x < 72) sw[threadIdx.x] = wT[threadIdx.x];
    if (threadIdx.x < 8)  sb[threadIdx.x] = b[threadIdx.x];
    __syncthreads();
    int t = blockIdx.x*256 + threadIdx.x;
    int owq = t & 31, oh = (t >> 5) & 127, n = t >> 12;
    int ow0 = owq*4;
    float acc[8][4];
    #pragma unroll
    for (int o = 0; o < 8; ++o) {
        float bv = sb[o];
        #pragma unroll
        for (int p = 0; p < 4; ++p) acc[o][p] = bv;
    }
    const float* ip = x + (size_t)n * 65536;
    #pragma unroll
    for (int kh = 0; kh < 3; ++kh) {
        int ih = oh*2 - 1 + kh;
        bool vh = (unsigned)ih < 256u;
        float v[9];
        #pragma unroll
        for (int i = 0; i < 9; ++i) {
            int iw = ow0*2 - 1 + i;
            v[i] = (vh && (unsigned)iw < 256u) ? ip[ih*256 + iw] : 0.f;
        }
        #pragma unroll
        for (int kw = 0; kw < 3; ++kw) {
            const float4* wp = (const float4*)(sw + (kh*3+kw)*8);
            #pragma unroll
            for (int q = 0; q < 2; ++q) {
                float4 wv = wp[q];
                #pragma unroll
                for (int p = 0; p < 4; ++p) {
                    float vv = v[kw + 2*p];
                    acc[q*4+0][p] = fmaf(vv, wv.x, acc[q*4+0][p]);
                    acc[q*4+1][p] = fmaf(vv, wv.y, acc[q*4+1][p]);
                    acc[q*4+2][p] = fmaf(vv, wv.z, acc[q*4+2][p]);
                    acc[q*4+3][p] = fmaf(vv, wv.w, acc[q*4+3][p]);
                }
            }
        }
    }
    size_t base = (size_t)n*131072 + (size_t)oh*128 + ow0;
    #pragma unroll
    for (int o = 0; o < 8; ++o) {
        bf tmp[4];
        #pragma unroll
        for (int p = 0; p < 4; ++p) tmp[p] = F2B(relu_(acc[o][p]));
        *(uint2*)(out + base + (size_t)o*16384) = *(uint2*)tmp;
    }
}

// conv2: bf16 [NB,8,128,128] -> bf16 ds[NB,32,64,64], 5x5 s2 p2, relu. 4 px/thread
__global__ void __launch_bounds__(256) conv2_k(const bf* __restrict__ in, const float* __restrict__ wT,
                        const float* __restrict__ b, bf* __restrict__ out) {
    __shared__ float sw[6400];
    __shared__ float sb[32];
    {
        const float4* s4 = (const float4*)wT;
        float4* d4 = (float4*)sw;
        for (int i = threadIdx.x; i < 1600; i += 256) d4[i] = s4[i];
        if (threadIdx.x < 32) sb[threadIdx.x] = b[threadIdx.x];
    }
    __syncthreads();
    int t = blockIdx.x*256 + threadIdx.x;
    int owq = t & 15, oh = (t >> 4) & 63, n = t >> 10;
    int ow0 = owq*4;
    float acc[32][4];
    #pragma unroll
    for (int o = 0; o < 32; ++o) {
        float bv = sb[o];
        #pragma unroll
        for (int p = 0; p < 4; ++p) acc[o][p] = bv;
    }
    for (int c = 0; c < 8; ++c) {
        const bf* ip = in + ((size_t)n*8 + c)*16384;
        #pragma unroll
        for (int kh = 0; kh < 5; ++kh) {
            int ih = oh*2 - 2 + kh;
            bool vh = (unsigned)ih < 128u;
            float v[13];
            #pragma unroll
            for (int i = 0; i < 13; ++i) {
                int iw = ow0*2 - 2 + i;
                v[i] = (vh && (unsigned)iw < 128u) ? B2F(ip[ih*128 + iw]) : 0.f;
            }
            #pragma unroll
            for (int kw = 0; kw < 5; ++kw) {
                const float4* wp = (const float4*)(sw + ((c*5+kh)*5+kw)*32);
                #pragma unroll
                for (int q = 0; q < 8; ++q) {
                    float4 wv = wp[q];
                    #pragma unroll
                    for (int p = 0; p < 4; ++p) {
                        float vv = v[kw + 2*p];
                        acc[q*4+0][p] = fmaf(vv, wv.x, acc[q*4+0][p]);
                        acc[q*4+1][p] = fmaf(vv, wv.y, acc[q*4+1][p]);
                        acc[q*4+2][p] = fmaf(vv, wv.z, acc[q*4+2][p]);
                        acc[q*4+3][p] = fmaf(vv, wv.w, acc[q*4+3][p]);
                    }
                }
            }
        }
    }
    size_t base = (size_t)n*131072 + (size_t)oh*64 + ow0;
    #pragma unroll
    for (int o = 0; o < 32; ++o) {
        bf tmp[4];
        #pragma unroll
        for (int p = 0; p < 4; ++p) tmp[p] = F2B(relu_(acc[o][p]));
        *(uint2*)(out + base + (size_t)o*4096) = *(uint2*)tmp;
    }
}

// conv3: bf16 ds[NB,32,64,64] -> fp32 [NB,4,32,32], 3x3 s2 p1, NO relu
__global__ void conv3_k(const bf* __restrict__ in, const float* __restrict__ wT,
                        const float* __restrict__ b, float* __restrict__ out) {
    __shared__ float sw[1152];
    __shared__ float sb[4];
    {
        const float4* s4 = (const float4*)wT;
        float4* d4 = (float4*)sw;
        for (int i = threadIdx.x; i < 288; i += 256) d4[i] = s4[i];
        if (threadIdx.x < 4) sb[threadIdx.x] = b[threadIdx.x];
    }
    __syncthreads();
    int t = blockIdx.x*256 + threadIdx.x;
    int ow = t & 31, oh = (t >> 5) & 31, n = t >> 10;
    float acc[4];
    #pragma unroll
    for (int o = 0; o < 4; ++o) acc[o] = sb[o];
    for (int c = 0; c < 32; ++c) {
        const bf* ip = in + ((size_t)n*32 + c)*4096;
        for (int kh = 0; kh < 3; ++kh) {
            int ih = oh*2 - 1 + kh;
            if ((unsigned)ih >= 64u) continue;
            for (int kw = 0; kw < 3; ++kw) {
                int iw = ow*2 - 1 + kw;
                if ((unsigned)iw >= 64u) continue;
                float v = B2F(ip[ih*64 + iw]);
                const float4* wp = (const float4*)(sw + ((c*3+kh)*3+kw)*4);
                float4 wv = wp[0];
                acc[0] = fmaf(v, wv.x, acc[0]);
                acc[1] = fmaf(v, wv.y, acc[1]);
                acc[2] = fmaf(v, wv.z, acc[2]);
                acc[3] = fmaf(v, wv.w, acc[3]);
            }
        }
    }
    size_t base = (size_t)n*4096 + (size_t)oh*32 + ow;
    #pragma unroll
    for (int o = 0; o < 4; ++o) out[base + (size_t)o*1024] = acc[o];
}

// conv4: fp32 [NB,4,32,32] -> fp32 [NB,20,16,16], 3x3 s2 p1, relu
__global__ void conv4_k(const float* __restrict__ in, const float* __restrict__ w,
                        const float* __restrict__ b, float* __restrict__ out) {
    int o = blockIdx.x % 20, n = blockIdx.x / 20;
    int hw = threadIdx.x, ow = hw & 15, oh = hw >> 4;
    float acc = b[o];
    for (int c = 0; c < 4; ++c) {
        const float* ip = in + ((size_t)n*4 + c)*1024;
        const float* wp = w + (o*4 + c)*9;
        for (int kh = 0; kh < 3; ++kh) {
            int ih = oh*2 - 1 + kh;
            if ((unsigned)ih >= 32u) continue;
            for (int kw = 0; kw < 3; ++kw) {
                int iw = ow*2 - 1 + kw;
                if ((unsigned)iw >= 32u) continue;
                acc = fmaf(ip[ih*32 + iw], wp[kh*3+kw], acc);
            }
        }
    }
    out[((size_t)n*20 + o)*256 + hw] = relu_(acc);
}

// conv5: [NB,20,16,16] -> [NB,30,8,8], 5x5 s2 p2, relu
__global__ void conv5_k(const float* __restrict__ in, const float* __restrict__ w,
                        const float* __restrict__ b, float* __restrict__ out) {
    int t = blockIdx.x*256 + threadIdx.x;
    int lane = t & 63, wid = t >> 6;
    int o = wid % 30, n = wid / 30;
    int ow = lane & 7, oh = lane >> 3;
    float acc = b[o];
    for (int c = 0; c < 20; ++c) {
        const float* ip = in + ((size_t)n*20 + c)*256;
        const float* wp = w + (o*20 + c)*25;
        for (int kh = 0; kh < 5; ++kh) {
            int ih = oh*2 - 2 + kh;
            if ((unsigned)ih >= 16u) continue;
            for (int kw = 0; kw < 5; ++kw) {
                int iw = ow*2 - 2 + kw;
                if ((unsigned)iw >= 16u) continue;
                acc = fmaf(ip[ih*16 + iw], wp[kh*5+kw], acc);
            }
        }
    }
    out[((size_t)n*30 + o)*64 + lane] = relu_(acc);
}

// conv6: [NB,30,8,8] -> [NB,8,4,4], 3x3 s2 p1, relu
__global__ void conv6_k(const float* __restrict__ in, const float* __restrict__ w,
                        const float* __restrict__ b, float* __restrict__ out) {
    int t = blockIdx.x*256 + threadIdx.x;
    int hw = t & 15, o = (t >> 4) & 7, n = t >> 7;
    int ow = hw & 3, oh = hw >> 2;
    float acc = b[o];
    for (int c = 0; c < 30; ++c) {
        const float* ip = in + ((size_t)n*30 + c)*64;
        const float* wp = w + (o*30 + c)*9;
        for (int kh = 0; kh < 3; ++kh) {
            int ih = oh*2 - 1 + kh;
            if ((unsigned)ih >= 8u) continue;
            for (int kw = 0; kw < 3; ++kw) {
                int iw = ow*2 - 1 + kw;
                if ((unsigned)iw >= 8u) continue;
                acc = fmaf(ip[ih*8 + iw], wp[kh*3+kw], acc);
            }
        }
    }
    out[((size_t)n*8 + o)*16 + hw] = relu_(acc);
}

// conv7: [NB,8,4,4] -> blur[NB,16]
__global__ void conv7_k(const float* __restrict__ in, const float* __restrict__ w,
                        const float* __restrict__ b, float* __restrict__ blur) {
    int t = blockIdx.x*256 + threadIdx.x;
    int pos = t & 15, n = t >> 4;
    float acc = b[0];
    for (int c = 0; c < 8; ++c) acc = fmaf(in[((size_t)n*8 + c)*16 + pos], w[c], acc);
    blur[n*16 + pos] = relu_(acc);
}

// blur channels of r1-conv are spatially constant -> per-(n, border-class, o) bias
__global__ void biasblur_k(const float* __restrict__ blur, const float* __restrict__ w1,
                           float* __restrict__ bb) {
    int t = blockIdx.x*256 + threadIdx.x;   // 128*9*64
    int o = t & 63, cls = (t >> 6) % 9, n = t / 576;
    int hc = cls / 3, wc = cls % 3;
    int kh0 = (hc == 0) ? 1 : 0, kh1 = (hc == 2) ? 1 : 2;
    int kw0 = (wc == 0) ? 1 : 0, kw1 = (wc == 2) ? 1 : 2;
    float s = 0.f;
    for (int c = 0; c < 16; ++c) {
        float bv = blur[n*16 + c];
        float ws = 0.f;
        for (int kh = kh0; kh <= kh1; ++kh)
            for (int kw = kw0; kw <= kw1; ++kw)
                ws += w1[((o*48 + c)*3 + kh)*3 + kw];
        s = fmaf(bv, ws, s);
    }
    bb[((size_t)n*9 + cls)*64 + o] = s;
}

// r1: 3x3 conv 32->64 + blur bias. 4 px/thread, out-ch split in 2 halves across blocks
__global__ void __launch_bounds__(256) r1conv_k(const bf* __restrict__ ds, const float* __restrict__ bb,
                         const float* __restrict__ bias, const float* __restrict__ wT,
                         bf* __restrict__ out) {
    __shared__ float sw[4608];   // 16ci x 9tap x 32oc
    int ohalf = blockIdx.x & 1;
    int oc0 = ohalf*32;
    int t = (blockIdx.x >> 1)*256 + threadIdx.x;
    int owq = t & 15, oh = (t >> 4) & 63, n = t >> 10;
    int ow0 = owq*4;
    int hc = (oh == 0) ? 0 : ((oh == 63) ? 2 : 1);
    float acc[32][4];
    const float* bb_n = bb + (size_t)n*576;
    #pragma unroll
    for (int p = 0; p < 4; ++p) {
        int ow = ow0 + p;
        int wc = (ow == 0) ? 0 : ((ow == 63) ? 2 : 1);
        const float* bbp = bb_n + (hc*3 + wc)*64 + oc0;
        #pragma unroll
        for (int o = 0; o < 32; ++o) acc[o][p] = bias[oc0+o] + bbp[o];
    }
    for (int cc = 0; cc < 2; ++cc) {
        __syncthreads();
        {
            float4* d4 = (float4*)sw;
            for (int i = threadIdx.x; i < 1152; i += 256) {
                int j4 = i & 7, tap = (i >> 3) % 9, ci = i / 72;
                d4[i] = *((const float4*)(wT + ((16 + cc*16 + ci)*9 + tap)*64 + oc0) + j4);
            }
        }
        __syncthreads();
        for (int ci = 0; ci < 16; ++ci) {
            const bf* ip = ds + ((size_t)n*32 + cc*16 + ci)*4096;
            #pragma unroll
            for (int kh = 0; kh < 3; ++kh) {
                int ih = oh - 1 + kh;
                bool vh = (unsigned)ih < 64u;
                float v[6];
                #pragma unroll
                for (int i = 0; i < 6; ++i) {
                    int iw = ow0 - 1 + i;
                    v[i] = (vh && (unsigned)iw < 64u) ? B2F(ip[ih*64 + iw]) : 0.f;
                }
                #pragma unroll
                for (int kw = 0; kw < 3; ++kw) {
                    const float4* wp = (const float4*)(sw + ((ci*3 + kh)*3 + kw)*32);
                    #pragma unroll
                    for (int q = 0; q < 8; ++q) {
                        float4 wv = wp[q];
                        #pragma unroll
                        for (int p = 0; p < 4; ++p) {
                            float vv = v[kw + p];
                            acc[q*4+0][p] = fmaf(vv, wv.x, acc[q*4+0][p]);
                            acc[q*4+1][p] = fmaf(vv, wv.y, acc[q*4+1][p]);
                            acc[q*4+2][p] = fmaf(vv, wv.z, acc[q*4+2][p]);
                            acc[q*4+3][p] = fmaf(vv, wv.w, acc[q*4+3][p]);
                        }
                    }
                }
            }
        }
    }
    size_t base = (size_t)n*262144 + (size_t)oh*64 + ow0;
    #pragma unroll
    for (int o = 0; o < 32; ++o) {
        bf tmp[4];
        #pragma unroll
        for (int p = 0; p < 4; ++p) tmp[p] = F2B(acc[o][p]);
        *(uint2*)(out + base + (size_t)(oc0 + o)*4096) = *(uint2*)tmp;
    }
}

// per-channel sum/sumsq over bf16 [NB,C,64,64]
template<int C, int BPC>
__global__ void stats_k(const bf* __restrict__ x, float* __restrict__ sums) {
    int c = blockIdx.x / BPC, bk = blockIdx.x % BPC;
    float s = 0.f, sq = 0.f;
    const int M = NB*4096;
    for (int i = bk*256 + threadIdx.x; i < M; i += BPC*256) {
        int n = i >> 12, r = i & 4095;
        float v = B2F(x[(((size_t)n*C + c) << 12) + r]);
        s += v; sq = fmaf(v, v, sq);
    }
    __shared__ float ls[256], lq[256];
    ls[threadIdx.x] = s; lq[threadIdx.x] = sq;
    __syncthreads();
    for (int st = 128; st > 0; st >>= 1) {
        if (threadIdx.x < st) { ls[threadIdx.x] += ls[threadIdx.x+st]; lq[threadIdx.x] += lq[threadIdx.x+st]; }
        __syncthreads();
    }
    if (threadIdx.x == 0) {
        atomicAdd(&sums[c*2], ls[0]);
        atomicAdd(&sums[c*2+1], lq[0]);
    }
}

// fold BN (training stats) into per-channel a*x + b
__global__ void fstats_k(const float* __restrict__ sums, const float* __restrict__ g,
                         const float* __restrict__ be, float* __restrict__ ab, int C) {
    int c = blockIdx.x*blockDim.x + threadIdx.x;
    if (c >= C) return;
    const float inv = 1.f / (float)(NB*4096);
    float mean = sums[c*2] * inv;
    float var  = sums[c*2+1] * inv - mean*mean;
    float a = g[c] * rsqrtf(var + 1e-5f);
    ab[c*2] = a;
    ab[c*2+1] = be[c] - mean*a;
}

// r2: 3x3 conv 64->20, input = relu(bn1(r1raw)) on the fly. 4 px/thread
__global__ void __launch_bounds__(256) r2conv_k(const bf* __restrict__ in, const float* __restrict__ ab1,
                         const float* __restrict__ bias, const float* __restrict__ wT,
                         bf* __restrict__ out) {
    __shared__ float sw[5760];   // 32ci x 9tap x 20oc
    __shared__ float sab[128];
    if (threadIdx.x < 128) sab[threadIdx.x] = ab1[threadIdx.x];
    int t = blockIdx.x*256 + threadIdx.x;
    int owq = t & 15, oh = (t >> 4) & 63, n = t >> 10;
    int ow0 = owq*4;
    float acc[20][4];
    #pragma unroll
    for (int o = 0; o < 20; ++o) {
        float bv = bias[o];
        #pragma unroll
        for (int p = 0; p < 4; ++p) acc[o][p] = bv;
    }
    for (int cc = 0; cc < 2; ++cc) {
        __syncthreads();
        {
            float4* d4 = (float4*)sw;
            for (int i = threadIdx.x; i < 1440; i += 256) {
                int j4 = i % 5, tap = (i/5) % 9, ci = i/45;
                d4[i] = *((const float4*)(wT + ((cc*32 + ci)*9 + tap)*20) + j4);
            }
        }
        __syncthreads();
        for (int ci = 0; ci < 32; ++ci) {
            int c = cc*32 + ci;
            float a = sab[c*2], bc = sab[c*2+1];
            const bf* ip = in + ((size_t)n*64 + c)*4096;
            #pragma unroll
            for (int kh = 0; kh < 3; ++kh) {
                int ih = oh - 1 + kh;
                bool vh = (unsigned)ih < 64u;
                float v[6];
                #pragma unroll
                for (int i = 0; i < 6; ++i) {
                    int iw = ow0 - 1 + i;
                    v[i] = (vh && (unsigned)iw < 64u) ? fmaxf(fmaf(B2F(ip[ih*64 + iw]), a, bc), 0.f) : 0.f;
                }
                #pragma unroll
                for (int kw = 0; kw < 3; ++kw) {
                    const float4* wp = (const float4*)(sw + ((ci*3 + kh)*3 + kw)*20);
                    #pragma unroll
                    for (int q = 0; q < 5; ++q) {
                        float4 wv = wp[q];
                        #pragma unroll
                        for (int p = 0; p < 4; ++p) {
                            float vv = v[kw + p];
                            acc[q*4+0][p] = fmaf(vv, wv.x, acc[q*4+0][p]);
                            acc[q*4+1][p] = fmaf(vv, wv.y, acc[q*4+1][p]);
                            acc[q*4+2][p] = fmaf(vv, wv.z, acc[q*4+2][p]);
                            acc[q*4+3][p] = fmaf(vv, wv.w, acc[q*4+3][p]);
                        }
                    }
                }
            }
        }
    }
    size_t base = (size_t)n*81920 + (size_t)oh*64 + ow0;
    #pragma unroll
    for (int o = 0; o < 20; ++o) {
        bf tmp[4];
        #pragma unroll
        for (int p = 0; p < 4; ++p) tmp[p] = F2B(acc[o][p]);
        *(uint2*)(out + base + (size_t)o*4096) = *(uint2*)tmp;
    }
}

// blur part of pointwise conv -> per-(n,o) scalar
__global__ void pwbias_k(const float* __restrict__ blur, const float* __restrict__ pw,
                         const float* __restrict__ pb, float* __restrict__ out) {
    int t = blockIdx.x*256 + threadIdx.x;   // 128*20
    if (t >= NB*20) return;
    int o = t % 20, n = t / 20;
    float s = pb[o];
    for (int c = 0; c < 16; ++c) s = fmaf(blur[n*16 + c], pw[o*48 + c], s);
    out[n*20 + o] = s;
}

// y = bn2(r2raw) + pw conv (ds channels) + pwb(blur part)
__global__ void finalize2_k(const bf* __restrict__ r2raw, const float* __restrict__ ab2,
                            const bf* __restrict__ ds, const float* __restrict__ pwT,
                            const float* __restrict__ pwb, bf* __restrict__ out) {
    __shared__ float sw[960];
    __shared__ float sab[40];
    {
        const float4* s4 = (const float4*)pwT;
        float4* d4 = (float4*)sw;
        if (threadIdx.x < 240) d4[threadIdx.x] = s4[threadIdx.x];
        if (threadIdx.x < 40) sab[threadIdx.x] = ab2[threadIdx.x];
    }
    __syncthreads();
    int t = blockIdx.x*256 + threadIdx.x;
    int hw = t & 4095, n = t >> 12;
    float acc[20];
    const float* pwbp = pwb + n*20;
    #pragma unroll
    for (int o = 0; o < 20; ++o) acc[o] = pwbp[o];
    for (int c = 0; c < 32; ++c) {
        float v = B2F(ds[((size_t)n*32 + c)*4096 + hw]);
        const float4* wp = (const float4*)(sw + (16 + c)*20);
        #pragma unroll
        for (int q = 0; q < 5; ++q) {
            float4 wv = wp[q];
            acc[q*4+0] = fmaf(v, wv.x, acc[q*4+0]);
            acc[q*4+1] = fmaf(v, wv.y, acc[q*4+1]);
            acc[q*4+2] = fmaf(v, wv.z, acc[q*4+2]);
            acc[q*4+3] = fmaf(v, wv.w, acc[q*4+3]);
        }
    }
    #pragma unroll
    for (int o = 0; o < 20; ++o) {
        size_t idx = ((size_t)n*20 + o)*4096 + hw;
        out[idx] = F2B(fmaf(B2F(r2raw[idx]), sab[o*2], sab[o*2+1]) + acc[o]);
    }
}

// u1: 3x3 conv 20->30, relu. 4 px/thread
__global__ void __launch_bounds__(256) u1conv_k(const bf* __restrict__ in, const float* __restrict__ bias,
                         const float* __restrict__ wT, bf* __restrict__ out) {
    __shared__ float sw[5400];
    __shared__ float sb[30];
    {
        const float4* s4 = (const float4*)wT;
        float4* d4 = (float4*)sw;
        for (int i = threadIdx.x; i < 1350; i += 256) d4[i] = s4[i];
        if (threadIdx.x < 30) sb[threadIdx.x] = bias[threadIdx.x];
    }
    __syncthreads();
    int t = blockIdx.x*256 + threadIdx.x;
    int owq = t & 15, oh = (t >> 4) & 63, n = t >> 10;
    int ow0 = owq*4;
    float acc[30][4];
    #pragma unroll
    for (int o = 0; o < 30; ++o) {
        float bv = sb[o];
        #pragma unroll
        for (int p = 0; p < 4; ++p) acc[o][p] = bv;
    }
    for (int c = 0; c < 20; ++c) {
        const bf* ip = in + ((size_t)n*20 + c)*4096;
        #pragma unroll
        for (int kh = 0; kh < 3; ++kh) {
            int ih = oh - 1 + kh;
            bool vh = (unsigned)ih < 64u;
            float v[6];
            #pragma unroll
            for (int i = 0; i < 6; ++i) {
                int iw = ow0 - 1 + i;
                v[i] = (vh && (unsigned)iw < 64u) ? B2F(ip[ih*64 + iw]) : 0.f;
            }
            #pragma unroll
            for (int kw = 0; kw < 3; ++kw) {
                const float2* wp = (const float2*)(sw + ((c*3+kh)*3+kw)*30);
                #pragma unroll
                for (int q = 0; q < 15; ++q) {
                    float2 wv = wp[q];
                    #pragma unroll
                    for (int p = 0; p < 4; ++p) {
                        float vv = v[kw + p];
                        acc[q*2+0][p] = fmaf(vv, wv.x, acc[q*2+0][p]);
                        acc[q*2+1][p] = fmaf(vv, wv.y, acc[q*2+1][p]);
                    }
                }
            }
        }
    }
    size_t base = (size_t)n*122880 + (size_t)oh*64 + ow0;
    #pragma unroll
    for (int o = 0; o < 30; ++o) {
        bf tmp[4];
        #pragma unroll
        for (int p = 0; p < 4; ++p) tmp[p] = F2B(relu_(acc[o][p]));
        *(uint2*)(out + base + (size_t)o*4096) = *(uint2*)tmp;
    }
}

// u2 1x1 (30->16) + relu + pixel_shuffle(4) + sigmoid -> FP32 out [NB,1,256,256]
__global__ void final_k(const bf* __restrict__ in, const float* __restrict__ wT,
                        const float* __restrict__ b, float* __restrict__ out) {
    __shared__ float sw[480];
    __shared__ float sb[16];
    {
        const float4* s4 = (const float4*)wT;
        float4* d4 = (float4*)sw;
        if (threadIdx.x < 120) d4[threadIdx.x] = s4[threadIdx.x];
        if (threadIdx.x < 16) sb[threadIdx.x] = b[threadIdx.x];
    }
    __syncthreads();
    int t = blockIdx.x*256 + threadIdx.x;
    int wcol = t & 63, h = (t >> 6) & 63, n = t >> 12;
    float acc[16];
    #pragma unroll
    for (int o = 0; o < 16; ++o) acc[o] = sb[o];
    for (int c = 0; c < 30; ++c) {
        float v = B2F(in[((size_t)n*30 + c)*4096 + h*64 + wcol]);
        const float4* wp = (const float4*)(sw + c*16);
        #pragma unroll
        for (int q = 0; q < 4; ++q) {
            float4 wv = wp[q];
            acc[q*4+0] = fmaf(v, wv.x, acc[q*4+0]);
            acc[q*4+1] = fmaf(v, wv.y, acc[q*4+1]);
            acc[q*4+2] = fmaf(v, wv.z, acc[q*4+2]);
            acc[q*4+3] = fmaf(v, wv.w, acc[q*4+3]);
        }
    }
    size_t ob = (size_t)n*65536;
    #pragma unroll
    for (int i = 0; i < 4; ++i) {
        float4 sv;
        float* sp = (float*)&sv;
        #pragma unroll
        for (int j = 0; j < 4; ++j) {
            float xv = fmaxf(acc[i*4+j], 0.f);
            sp[j] = 1.f / (1.f + __expf(-xv));
        }
        *(float4*)(out + ob + (size_t)(h*4+i)*256 + wcol*4) = sv;
    }
}

extern "C" void kernel_launch(void* const* d_in, const int* in_sizes, int n_in,
                              void* d_out, int out_size, void* d_ws, size_t ws_size,
                              hipStream_t stream) {
    (void)in_sizes; (void)n_in; (void)out_size;
    const float* x   = (const float*)d_in[0];
    const float* c1w = (const float*)d_in[1];  const float* c1b = (const float*)d_in[2];
    const float* c2w = (const float*)d_in[3];  const float* c2b = (const float*)d_in[4];
    const float* c3w = (const float*)d_in[5];  const float* c3b = (const float*)d_in[6];
    const float* c4w = (const float*)d_in[7];  const float* c4b = (const float*)d_in[8];
    const float* c5w = (const float*)d_in[9];  const float* c5b = (const float*)d_in[10];
    const float* c6w = (const float*)d_in[11]; const float* c6b = (const float*)d_in[12];
    const float* c7w = (const float*)d_in[13]; const float* c7b = (const float*)d_in[14];
    const float* r1w = (const float*)d_in[15]; const float* r1b = (const float*)d_in[16];
    const float* g1  = (const float*)d_in[17]; const float* be1 = (const float*)d_in[18];
    const float* r2w = (const float*)d_in[19]; const float* r2b = (const float*)d_in[20];
    const float* g2  = (const float*)d_in[21]; const float* be2 = (const float*)d_in[22];
    const float* pw  = (const float*)d_in[23]; const float* pb  = (const float*)d_in[24];
    const float* u1w = (const float*)d_in[25]; const float* u1b = (const float*)d_in[26];
    const float* u2w = (const float*)d_in[27]; const float* u2b = (const float*)d_in[28];
    float* out = (float*)d_out;

    char* base = (char*)d_ws;
    size_t cur = 0;
    auto alloc = [&](size_t bytes) -> char* {
        char* p = base + cur;
        cur = (cur + bytes + 255) & ~((size_t)255);
        return p;
    };
    bf* ds_bf   = (bf*)alloc(33554432);   // [128,32,64,64] bf16
    char* A     = alloc(67108864);        // region A: t1 -> r1raw -> (ybuf, u1out)
    bf* t1_bf   = (bf*)A;
    bf* r1raw   = (bf*)A;
    bf* ybuf    = (bf*)A;
    bf* u1out   = (bf*)(A + 33554432);
    bf* r2raw   = (bf*)alloc(20971520);
    float* t3   = (float*)alloc(2097152);
    float* t4   = (float*)alloc(2621440);
    float* t5   = (float*)alloc(983040);
    float* t6   = (float*)alloc(65536);
    float* blur = (float*)alloc(8192);
    float* bb   = (float*)alloc(294912);
    float* pwb  = (float*)alloc(10240);
    float* stats  = (float*)alloc(672);
    float* stats2 = stats + 128;
    float* ab1  = (float*)alloc(512);
    float* ab2  = (float*)alloc(160);
    float* wTc1 = (float*)alloc(288);
    float* wTc2 = (float*)alloc(25600);
    float* wTc3 = (float*)alloc(4608);
    float* wTr1 = (float*)alloc(110592);
    float* wTr2 = (float*)alloc(46080);
    float* wTu1 = (float*)alloc(21600);
    float* wTu2 = (float*)alloc(1920);
    float* pwT  = (float*)alloc(3840);

    if (ws_size < cur) return;

    hipMemsetAsync(stats, 0, 672, stream);

    auto tr = [&](const float* s, float* d, int O, int CK) {
        int n = O*CK;
        transpose_w<<<(n + 255)/256, 256, 0, stream>>>(s, d, O, CK);
    };
    tr(c1w, wTc1, 8, 9);
    tr(c2w, wTc2, 32, 200);
    tr(c3w, wTc3, 4, 288);
    tr(r1w, wTr1, 64, 432);
    tr(r2w, wTr2, 20, 576);
    tr(u1w, wTu1, 30, 180);
    tr(u2w, wTu2, 16, 30);
    tr(pw,  pwT,  20, 48);

    conv1_k<<<2048, 256, 0, stream>>>(x, wTc1, c1b, t1_bf);
    conv2_k<<<512, 256, 0, stream>>>(t1_bf, wTc2, c2b, ds_bf);
    conv3_k<<<512, 256, 0, stream>>>(ds_bf, wTc3, c3b, t3);
    conv4_k<<<2560, 256, 0, stream>>>(t3, c4w, c4b, t4);
    conv5_k<<<960, 256, 0, stream>>>(t4, c5w, c5b, t5);
    conv6_k<<<64, 256, 0, stream>>>(t5, c6w, c6b, t6);
    conv7_k<<<8, 256, 0, stream>>>(t6, c7w, c7b, blur);
    biasblur_k<<<288, 256, 0, stream>>>(blur, r1w, bb);
    r1conv_k<<<1024, 256, 0, stream>>>(ds_bf, bb, r1b, wTr1, r1raw);
    stats_k<64, 32><<<2048, 256, 0, stream>>>(r1raw, stats);
    fstats_k<<<1, 64, 0, stream>>>(stats, g1, be1, ab1, 64);
    r2conv_k<<<512, 256, 0, stream>>>(r1raw, ab1, r2b, wTr2, r2raw);
    stats_k<20, 32><<<640, 256, 0, stream>>>(r2raw, stats2);
    fstats_k<<<1, 32, 0, stream>>>(stats2, g2, be2, ab2, 20);
    pwbias_k<<<10, 256, 0, stream>>>(blur, pw, pb, pwb);
    finalize2_k<<<2048, 256, 0, stream>>>(r2raw, ab2, ds_bf, pwT, pwb, ybuf);
    u1conv_k<<<512, 256, 0, stream>>>(ybuf, u1b, wTu1, u1out);
    final_k<<<2048, 256, 0, stream>>>(u1out, wTu2, u2b, out);
}

// Round 9
// 1820.722 us; speedup vs baseline: 1.1504x; 1.1504x over previous
//
#include <hip/hip_runtime.h>
#include <hip/hip_bf16.h>

#define NB 128
typedef __hip_bfloat16 bf;

__device__ __forceinline__ float relu_(float x){ return fmaxf(x, 0.f); }
__device__ __forceinline__ float B2F(bf v){ return __bfloat162float(v); }
__device__ __forceinline__ bf F2B(float v){ return __float2bfloat16(v); }

// transpose w[O][CK] -> wT[CK][O]
__global__ void transpose_w(const float* __restrict__ src, float* __restrict__ dst, int O, int CK) {
    int t = blockIdx.x*blockDim.x + threadIdx.x;
    if (t >= O*CK) return;
    int o = t / CK, ck = t - o*CK;
    dst[ck*O + o] = src[t];
}

// conv1: x[NB,1,256,256] fp32 -> bf16 [NB,8,128,128], 3x3 s2 p1, relu. 4 px/thread (32 acc)
__global__ void conv1_k(const float* __restrict__ x, const float* __restrict__ wT,
                        const float* __restrict__ b, bf* __restrict__ out) {
    __shared__ float sw[72];
    __shared__ float sb[8];
    if (threadIdx.x < 72) sw[threadIdx.x] = wT[threadIdx.x];
    if (threadIdx.x < 8)  sb[threadIdx.x] = b[threadIdx.x];
    __syncthreads();
    int t = blockIdx.x*256 + threadIdx.x;
    int owq = t & 31, oh = (t >> 5) & 127, n = t >> 12;
    int ow0 = owq*4;
    float acc[8][4];
    #pragma unroll
    for (int o = 0; o < 8; ++o) {
        float bv = sb[o];
        #pragma unroll
        for (int p = 0; p < 4; ++p) acc[o][p] = bv;
    }
    const float* ip = x + (size_t)n * 65536;
    #pragma unroll
    for (int kh = 0; kh < 3; ++kh) {
        int ih = oh*2 - 1 + kh;
        bool vh = (unsigned)ih < 256u;
        float v[9];
        #pragma unroll
        for (int i = 0; i < 9; ++i) {
            int iw = ow0*2 - 1 + i;
            v[i] = (vh && (unsigned)iw < 256u) ? ip[ih*256 + iw] : 0.f;
        }
        #pragma unroll
        for (int kw = 0; kw < 3; ++kw) {
            const float4* wp = (const float4*)(sw + (kh*3+kw)*8);
            #pragma unroll
            for (int q = 0; q < 2; ++q) {
                float4 wv = wp[q];
                #pragma unroll
                for (int p = 0; p < 4; ++p) {
                    float vv = v[kw + 2*p];
                    acc[q*4+0][p] = fmaf(vv, wv.x, acc[q*4+0][p]);
                    acc[q*4+1][p] = fmaf(vv, wv.y, acc[q*4+1][p]);
                    acc[q*4+2][p] = fmaf(vv, wv.z, acc[q*4+2][p]);
                    acc[q*4+3][p] = fmaf(vv, wv.w, acc[q*4+3][p]);
                }
            }
        }
    }
    size_t base = (size_t)n*131072 + (size_t)oh*128 + ow0;
    #pragma unroll
    for (int o = 0; o < 8; ++o) {
        bf tmp[4];
        #pragma unroll
        for (int p = 0; p < 4; ++p) tmp[p] = F2B(relu_(acc[o][p]));
        *(uint2*)(out + base + (size_t)o*16384) = *(uint2*)tmp;
    }
}

// conv2: bf16 [NB,8,128,128] -> bf16 ds[NB,32,64,64], 5x5 s2 p2, relu.
// 4 px/thread, out-ch split x2 (16 oc x 4 px = 64 acc regs)
__global__ void __launch_bounds__(256) conv2_k(const bf* __restrict__ in, const float* __restrict__ wT,
                        const float* __restrict__ b, bf* __restrict__ out) {
    __shared__ float sw[3200];   // 8ci x 25tap x 16oc
    __shared__ float sb[16];
    int ohalf = blockIdx.x & 1;
    int oc0 = ohalf*16;
    {
        float4* d4 = (float4*)sw;
        for (int i = threadIdx.x; i < 800; i += 256) {
            int j4 = i & 3, ck = i >> 2;
            d4[i] = *((const float4*)(wT + ck*32 + oc0) + j4);
        }
        if (threadIdx.x < 16) sb[threadIdx.x] = b[oc0 + threadIdx.x];
    }
    __syncthreads();
    int t = (blockIdx.x >> 1)*256 + threadIdx.x;
    int owq = t & 15, oh = (t >> 4) & 63, n = t >> 10;
    int ow0 = owq*4;
    float acc[16][4];
    #pragma unroll
    for (int o = 0; o < 16; ++o) {
        float bv = sb[o];
        #pragma unroll
        for (int p = 0; p < 4; ++p) acc[o][p] = bv;
    }
    for (int c = 0; c < 8; ++c) {
        const bf* ip = in + ((size_t)n*8 + c)*16384;
        #pragma unroll
        for (int kh = 0; kh < 5; ++kh) {
            int ih = oh*2 - 2 + kh;
            bool vh = (unsigned)ih < 128u;
            float v[13];
            #pragma unroll
            for (int i = 0; i < 13; ++i) {
                int iw = ow0*2 - 2 + i;
                v[i] = (vh && (unsigned)iw < 128u) ? B2F(ip[ih*128 + iw]) : 0.f;
            }
            #pragma unroll
            for (int kw = 0; kw < 5; ++kw) {
                const float4* wp = (const float4*)(sw + ((c*5+kh)*5+kw)*16);
                #pragma unroll
                for (int q = 0; q < 4; ++q) {
                    float4 wv = wp[q];
                    #pragma unroll
                    for (int p = 0; p < 4; ++p) {
                        float vv = v[kw + 2*p];
                        acc[q*4+0][p] = fmaf(vv, wv.x, acc[q*4+0][p]);
                        acc[q*4+1][p] = fmaf(vv, wv.y, acc[q*4+1][p]);
                        acc[q*4+2][p] = fmaf(vv, wv.z, acc[q*4+2][p]);
                        acc[q*4+3][p] = fmaf(vv, wv.w, acc[q*4+3][p]);
                    }
                }
            }
        }
    }
    size_t base = (size_t)n*131072 + (size_t)oh*64 + ow0;
    #pragma unroll
    for (int o = 0; o < 16; ++o) {
        bf tmp[4];
        #pragma unroll
        for (int p = 0; p < 4; ++p) tmp[p] = F2B(relu_(acc[o][p]));
        *(uint2*)(out + base + (size_t)(oc0 + o)*4096) = *(uint2*)tmp;
    }
}

// conv3: bf16 ds[NB,32,64,64] -> fp32 [NB,4,32,32], 3x3 s2 p1, NO relu
__global__ void conv3_k(const bf* __restrict__ in, const float* __restrict__ wT,
                        const float* __restrict__ b, float* __restrict__ out) {
    __shared__ float sw[1152];
    __shared__ float sb[4];
    {
        const float4* s4 = (const float4*)wT;
        float4* d4 = (float4*)sw;
        for (int i = threadIdx.x; i < 288; i += 256) d4[i] = s4[i];
        if (threadIdx.x < 4) sb[threadIdx.x] = b[threadIdx.x];
    }
    __syncthreads();
    int t = blockIdx.x*256 + threadIdx.x;
    int ow = t & 31, oh = (t >> 5) & 31, n = t >> 10;
    float acc[4];
    #pragma unroll
    for (int o = 0; o < 4; ++o) acc[o] = sb[o];
    for (int c = 0; c < 32; ++c) {
        const bf* ip = in + ((size_t)n*32 + c)*4096;
        for (int kh = 0; kh < 3; ++kh) {
            int ih = oh*2 - 1 + kh;
            if ((unsigned)ih >= 64u) continue;
            for (int kw = 0; kw < 3; ++kw) {
                int iw = ow*2 - 1 + kw;
                if ((unsigned)iw >= 64u) continue;
                float v = B2F(ip[ih*64 + iw]);
                const float4* wp = (const float4*)(sw + ((c*3+kh)*3+kw)*4);
                float4 wv = wp[0];
                acc[0] = fmaf(v, wv.x, acc[0]);
                acc[1] = fmaf(v, wv.y, acc[1]);
                acc[2] = fmaf(v, wv.z, acc[2]);
                acc[3] = fmaf(v, wv.w, acc[3]);
            }
        }
    }
    size_t base = (size_t)n*4096 + (size_t)oh*32 + ow;
    #pragma unroll
    for (int o = 0; o < 4; ++o) out[base + (size_t)o*1024] = acc[o];
}

// conv4: fp32 [NB,4,32,32] -> fp32 [NB,20,16,16], 3x3 s2 p1, relu
__global__ void conv4_k(const float* __restrict__ in, const float* __restrict__ w,
                        const float* __restrict__ b, float* __restrict__ out) {
    int o = blockIdx.x % 20, n = blockIdx.x / 20;
    int hw = threadIdx.x, ow = hw & 15, oh = hw >> 4;
    float acc = b[o];
    for (int c = 0; c < 4; ++c) {
        const float* ip = in + ((size_t)n*4 + c)*1024;
        const float* wp = w + (o*4 + c)*9;
        for (int kh = 0; kh < 3; ++kh) {
            int ih = oh*2 - 1 + kh;
            if ((unsigned)ih >= 32u) continue;
            for (int kw = 0; kw < 3; ++kw) {
                int iw = ow*2 - 1 + kw;
                if ((unsigned)iw >= 32u) continue;
                acc = fmaf(ip[ih*32 + iw], wp[kh*3+kw], acc);
            }
        }
    }
    out[((size_t)n*20 + o)*256 + hw] = relu_(acc);
}

// conv5: [NB,20,16,16] -> [NB,30,8,8], 5x5 s2 p2, relu
__global__ void conv5_k(const float* __restrict__ in, const float* __restrict__ w,
                        const float* __restrict__ b, float* __restrict__ out) {
    int t = blockIdx.x*256 + threadIdx.x;
    int lane = t & 63, wid = t >> 6;
    int o = wid % 30, n = wid / 30;
    int ow = lane & 7, oh = lane >> 3;
    float acc = b[o];
    for (int c = 0; c < 20; ++c) {
        const float* ip = in + ((size_t)n*20 + c)*256;
        const float* wp = w + (o*20 + c)*25;
        for (int kh = 0; kh < 5; ++kh) {
            int ih = oh*2 - 2 + kh;
            if ((unsigned)ih >= 16u) continue;
            for (int kw = 0; kw < 5; ++kw) {
                int iw = ow*2 - 2 + kw;
                if ((unsigned)iw >= 16u) continue;
                acc = fmaf(ip[ih*16 + iw], wp[kh*5+kw], acc);
            }
        }
    }
    out[((size_t)n*30 + o)*64 + lane] = relu_(acc);
}

// conv6: [NB,30,8,8] -> [NB,8,4,4], 3x3 s2 p1, relu
__global__ void conv6_k(const float* __restrict__ in, const float* __restrict__ w,
                        const float* __restrict__ b, float* __restrict__ out) {
    int t = blockIdx.x*256 + threadIdx.x;
    int hw = t & 15, o = (t >> 4) & 7, n = t >> 7;
    int ow = hw & 3, oh = hw >> 2;
    float acc = b[o];
    for (int c = 0; c < 30; ++c) {
        const float* ip = in + ((size_t)n*30 + c)*64;
        const float* wp = w + (o*30 + c)*9;
        for (int kh = 0; kh < 3; ++kh) {
            int ih = oh*2 - 1 + kh;
            if ((unsigned)ih >= 8u) continue;
            for (int kw = 0; kw < 3; ++kw) {
                int iw = ow*2 - 1 + kw;
                if ((unsigned)iw >= 8u) continue;
                acc = fmaf(ip[ih*8 + iw], wp[kh*3+kw], acc);
            }
        }
    }
    out[((size_t)n*8 + o)*16 + hw] = relu_(acc);
}

// conv7: [NB,8,4,4] -> blur[NB,16]
__global__ void conv7_k(const float* __restrict__ in, const float* __restrict__ w,
                        const float* __restrict__ b, float* __restrict__ blur) {
    int t = blockIdx.x*256 + threadIdx.x;
    int pos = t & 15, n = t >> 4;
    float acc = b[0];
    for (int c = 0; c < 8; ++c) acc = fmaf(in[((size_t)n*8 + c)*16 + pos], w[c], acc);
    blur[n*16 + pos] = relu_(acc);
}

// blur channels of r1-conv are spatially constant -> per-(n, border-class, o) bias
__global__ void biasblur_k(const float* __restrict__ blur, const float* __restrict__ w1,
                           float* __restrict__ bb) {
    int t = blockIdx.x*256 + threadIdx.x;   // 128*9*64
    int o = t & 63, cls = (t >> 6) % 9, n = t / 576;
    int hc = cls / 3, wc = cls % 3;
    int kh0 = (hc == 0) ? 1 : 0, kh1 = (hc == 2) ? 1 : 2;
    int kw0 = (wc == 0) ? 1 : 0, kw1 = (wc == 2) ? 1 : 2;
    float s = 0.f;
    for (int c = 0; c < 16; ++c) {
        float bv = blur[n*16 + c];
        float ws = 0.f;
        for (int kh = kh0; kh <= kh1; ++kh)
            for (int kw = kw0; kw <= kw1; ++kw)
                ws += w1[((o*48 + c)*3 + kh)*3 + kw];
        s = fmaf(bv, ws, s);
    }
    bb[((size_t)n*9 + cls)*64 + o] = s;
}

// r1: 3x3 conv 32->64 + blur bias. 2 px/thread, oc-split x2 (32 oc x 2 px = 64 acc)
__global__ void __launch_bounds__(256) r1conv_k(const bf* __restrict__ ds, const float* __restrict__ bb,
                         const float* __restrict__ bias, const float* __restrict__ wT,
                         bf* __restrict__ out) {
    __shared__ float sw[4608];   // 16ci x 9tap x 32oc
    int ohalf = blockIdx.x & 1;
    int oc0 = ohalf*32;
    int t = (blockIdx.x >> 1)*256 + threadIdx.x;
    int owq = t & 31, oh = (t >> 5) & 63, n = t >> 11;
    int ow0 = owq*2;
    int hc = (oh == 0) ? 0 : ((oh == 63) ? 2 : 1);
    float acc[32][2];
    const float* bb_n = bb + (size_t)n*576;
    #pragma unroll
    for (int p = 0; p < 2; ++p) {
        int ow = ow0 + p;
        int wc = (ow == 0) ? 0 : ((ow == 63) ? 2 : 1);
        const float* bbp = bb_n + (hc*3 + wc)*64 + oc0;
        #pragma unroll
        for (int o = 0; o < 32; ++o) acc[o][p] = bias[oc0+o] + bbp[o];
    }
    for (int cc = 0; cc < 2; ++cc) {
        __syncthreads();
        {
            float4* d4 = (float4*)sw;
            for (int i = threadIdx.x; i < 1152; i += 256) {
                int j4 = i & 7, tap = (i >> 3) % 9, ci = i / 72;
                d4[i] = *((const float4*)(wT + ((16 + cc*16 + ci)*9 + tap)*64 + oc0) + j4);
            }
        }
        __syncthreads();
        for (int ci = 0; ci < 16; ++ci) {
            const bf* ip = ds + ((size_t)n*32 + cc*16 + ci)*4096;
            #pragma unroll
            for (int kh = 0; kh < 3; ++kh) {
                int ih = oh - 1 + kh;
                bool vh = (unsigned)ih < 64u;
                float v[4];
                #pragma unroll
                for (int i = 0; i < 4; ++i) {
                    int iw = ow0 - 1 + i;
                    v[i] = (vh && (unsigned)iw < 64u) ? B2F(ip[ih*64 + iw]) : 0.f;
                }
                #pragma unroll
                for (int kw = 0; kw < 3; ++kw) {
                    const float4* wp = (const float4*)(sw + ((ci*3 + kh)*3 + kw)*32);
                    #pragma unroll
                    for (int q = 0; q < 8; ++q) {
                        float4 wv = wp[q];
                        #pragma unroll
                        for (int p = 0; p < 2; ++p) {
                            float vv = v[kw + p];
                            acc[q*4+0][p] = fmaf(vv, wv.x, acc[q*4+0][p]);
                            acc[q*4+1][p] = fmaf(vv, wv.y, acc[q*4+1][p]);
                            acc[q*4+2][p] = fmaf(vv, wv.z, acc[q*4+2][p]);
                            acc[q*4+3][p] = fmaf(vv, wv.w, acc[q*4+3][p]);
                        }
                    }
                }
            }
        }
    }
    size_t base = (size_t)n*262144 + (size_t)oh*64 + ow0;
    #pragma unroll
    for (int o = 0; o < 32; ++o) {
        bf tmp[2];
        tmp[0] = F2B(acc[o][0]);
        tmp[1] = F2B(acc[o][1]);
        *(uint*)(out + base + (size_t)(oc0 + o)*4096) = *(uint*)tmp;
    }
}

// per-channel sum/sumsq over bf16 [NB,C,64,64]
template<int C, int BPC>
__global__ void stats_k(const bf* __restrict__ x, float* __restrict__ sums) {
    int c = blockIdx.x / BPC, bk = blockIdx.x % BPC;
    float s = 0.f, sq = 0.f;
    const int M = NB*4096;
    for (int i = bk*256 + threadIdx.x; i < M; i += BPC*256) {
        int n = i >> 12, r = i & 4095;
        float v = B2F(x[(((size_t)n*C + c) << 12) + r]);
        s += v; sq = fmaf(v, v, sq);
    }
    __shared__ float ls[256], lq[256];
    ls[threadIdx.x] = s; lq[threadIdx.x] = sq;
    __syncthreads();
    for (int st = 128; st > 0; st >>= 1) {
        if (threadIdx.x < st) { ls[threadIdx.x] += ls[threadIdx.x+st]; lq[threadIdx.x] += lq[threadIdx.x+st]; }
        __syncthreads();
    }
    if (threadIdx.x == 0) {
        atomicAdd(&sums[c*2], ls[0]);
        atomicAdd(&sums[c*2+1], lq[0]);
    }
}

// fold BN (training stats) into per-channel a*x + b
__global__ void fstats_k(const float* __restrict__ sums, const float* __restrict__ g,
                         const float* __restrict__ be, float* __restrict__ ab, int C) {
    int c = blockIdx.x*blockDim.x + threadIdx.x;
    if (c >= C) return;
    const float inv = 1.f / (float)(NB*4096);
    float mean = sums[c*2] * inv;
    float var  = sums[c*2+1] * inv - mean*mean;
    float a = g[c] * rsqrtf(var + 1e-5f);
    ab[c*2] = a;
    ab[c*2+1] = be[c] - mean*a;
}

// r2: 3x3 conv 64->20, input = relu(bn1(r1raw)) on the fly. 4 px/thread (80 acc)
__global__ void __launch_bounds__(256) r2conv_k(const bf* __restrict__ in, const float* __restrict__ ab1,
                         const float* __restrict__ bias, const float* __restrict__ wT,
                         bf* __restrict__ out) {
    __shared__ float sw[5760];   // 32ci x 9tap x 20oc
    __shared__ float sab[128];
    if (threadIdx.x < 128) sab[threadIdx.x] = ab1[threadIdx.x];
    int t = blockIdx.x*256 + threadIdx.x;
    int owq = t & 15, oh = (t >> 4) & 63, n = t >> 10;
    int ow0 = owq*4;
    float acc[20][4];
    #pragma unroll
    for (int o = 0; o < 20; ++o) {
        float bv = bias[o];
        #pragma unroll
        for (int p = 0; p < 4; ++p) acc[o][p] = bv;
    }
    for (int cc = 0; cc < 2; ++cc) {
        __syncthreads();
        {
            float4* d4 = (float4*)sw;
            for (int i = threadIdx.x; i < 1440; i += 256) {
                int j4 = i % 5, tap = (i/5) % 9, ci = i/45;
                d4[i] = *((const float4*)(wT + ((cc*32 + ci)*9 + tap)*20) + j4);
            }
        }
        __syncthreads();
        for (int ci = 0; ci < 32; ++ci) {
            int c = cc*32 + ci;
            float a = sab[c*2], bc = sab[c*2+1];
            const bf* ip = in + ((size_t)n*64 + c)*4096;
            #pragma unroll
            for (int kh = 0; kh < 3; ++kh) {
                int ih = oh - 1 + kh;
                bool vh = (unsigned)ih < 64u;
                float v[6];
                #pragma unroll
                for (int i = 0; i < 6; ++i) {
                    int iw = ow0 - 1 + i;
                    v[i] = (vh && (unsigned)iw < 64u) ? fmaxf(fmaf(B2F(ip[ih*64 + iw]), a, bc), 0.f) : 0.f;
                }
                #pragma unroll
                for (int kw = 0; kw < 3; ++kw) {
                    const float4* wp = (const float4*)(sw + ((ci*3 + kh)*3 + kw)*20);
                    #pragma unroll
                    for (int q = 0; q < 5; ++q) {
                        float4 wv = wp[q];
                        #pragma unroll
                        for (int p = 0; p < 4; ++p) {
                            float vv = v[kw + p];
                            acc[q*4+0][p] = fmaf(vv, wv.x, acc[q*4+0][p]);
                            acc[q*4+1][p] = fmaf(vv, wv.y, acc[q*4+1][p]);
                            acc[q*4+2][p] = fmaf(vv, wv.z, acc[q*4+2][p]);
                            acc[q*4+3][p] = fmaf(vv, wv.w, acc[q*4+3][p]);
                        }
                    }
                }
            }
        }
    }
    size_t base = (size_t)n*81920 + (size_t)oh*64 + ow0;
    #pragma unroll
    for (int o = 0; o < 20; ++o) {
        bf tmp[4];
        #pragma unroll
        for (int p = 0; p < 4; ++p) tmp[p] = F2B(acc[o][p]);
        *(uint2*)(out + base + (size_t)o*4096) = *(uint2*)tmp;
    }
}

// blur part of pointwise conv -> per-(n,o) scalar
__global__ void pwbias_k(const float* __restrict__ blur, const float* __restrict__ pw,
                         const float* __restrict__ pb, float* __restrict__ out) {
    int t = blockIdx.x*256 + threadIdx.x;   // 128*20
    if (t >= NB*20) return;
    int o = t % 20, n = t / 20;
    float s = pb[o];
    for (int c = 0; c < 16; ++c) s = fmaf(blur[n*16 + c], pw[o*48 + c], s);
    out[n*20 + o] = s;
}

// y = bn2(r2raw) + pw conv (ds channels) + pwb(blur part)
__global__ void finalize2_k(const bf* __restrict__ r2raw, const float* __restrict__ ab2,
                            const bf* __restrict__ ds, const float* __restrict__ pwT,
                            const float* __restrict__ pwb, bf* __restrict__ out) {
    __shared__ float sw[960];
    __shared__ float sab[40];
    {
        const float4* s4 = (const float4*)pwT;
        float4* d4 = (float4*)sw;
        if (threadIdx.x < 240) d4[threadIdx.x] = s4[threadIdx.x];
        if (threadIdx.x < 40) sab[threadIdx.x] = ab2[threadIdx.x];
    }
    __syncthreads();
    int t = blockIdx.x*256 + threadIdx.x;
    int hw = t & 4095, n = t >> 12;
    float acc[20];
    const float* pwbp = pwb + n*20;
    #pragma unroll
    for (int o = 0; o < 20; ++o) acc[o] = pwbp[o];
    for (int c = 0; c < 32; ++c) {
        float v = B2F(ds[((size_t)n*32 + c)*4096 + hw]);
        const float4* wp = (const float4*)(sw + (16 + c)*20);
        #pragma unroll
        for (int q = 0; q < 5; ++q) {
            float4 wv = wp[q];
            acc[q*4+0] = fmaf(v, wv.x, acc[q*4+0]);
            acc[q*4+1] = fmaf(v, wv.y, acc[q*4+1]);
            acc[q*4+2] = fmaf(v, wv.z, acc[q*4+2]);
            acc[q*4+3] = fmaf(v, wv.w, acc[q*4+3]);
        }
    }
    #pragma unroll
    for (int o = 0; o < 20; ++o) {
        size_t idx = ((size_t)n*20 + o)*4096 + hw;
        out[idx] = F2B(fmaf(B2F(r2raw[idx]), sab[o*2], sab[o*2+1]) + acc[o]);
    }
}

// u1: 3x3 conv 20->30, relu. 2 px/thread (60 acc)
__global__ void __launch_bounds__(256) u1conv_k(const bf* __restrict__ in, const float* __restrict__ bias,
                         const float* __restrict__ wT, bf* __restrict__ out) {
    __shared__ float sw[5400];
    __shared__ float sb[30];
    {
        const float4* s4 = (const float4*)wT;
        float4* d4 = (float4*)sw;
        for (int i = threadIdx.x; i < 1350; i += 256) d4[i] = s4[i];
        if (threadIdx.x < 30) sb[threadIdx.x] = bias[threadIdx.x];
    }
    __syncthreads();
    int t = blockIdx.x*256 + threadIdx.x;
    int owq = t & 31, oh = (t >> 5) & 63, n = t >> 11;
    int ow0 = owq*2;
    float acc[30][2];
    #pragma unroll
    for (int o = 0; o < 30; ++o) {
        float bv = sb[o];
        acc[o][0] = bv; acc[o][1] = bv;
    }
    for (int c = 0; c < 20; ++c) {
        const bf* ip = in + ((size_t)n*20 + c)*4096;
        #pragma unroll
        for (int kh = 0; kh < 3; ++kh) {
            int ih = oh - 1 + kh;
            bool vh = (unsigned)ih < 64u;
            float v[4];
            #pragma unroll
            for (int i = 0; i < 4; ++i) {
                int iw = ow0 - 1 + i;
                v[i] = (vh && (unsigned)iw < 64u) ? B2F(ip[ih*64 + iw]) : 0.f;
            }
            #pragma unroll
            for (int kw = 0; kw < 3; ++kw) {
                const float2* wp = (const float2*)(sw + ((c*3+kh)*3+kw)*30);
                #pragma unroll
                for (int q = 0; q < 15; ++q) {
                    float2 wv = wp[q];
                    #pragma unroll
                    for (int p = 0; p < 2; ++p) {
                        float vv = v[kw + p];
                        acc[q*2+0][p] = fmaf(vv, wv.x, acc[q*2+0][p]);
                        acc[q*2+1][p] = fmaf(vv, wv.y, acc[q*2+1][p]);
                    }
                }
            }
        }
    }
    size_t base = (size_t)n*122880 + (size_t)oh*64 + ow0;
    #pragma unroll
    for (int o = 0; o < 30; ++o) {
        bf tmp[2];
        tmp[0] = F2B(relu_(acc[o][0]));
        tmp[1] = F2B(relu_(acc[o][1]));
        *(uint*)(out + base + (size_t)o*4096) = *(uint*)tmp;
    }
}

// u2 1x1 (30->16) + relu + pixel_shuffle(4) + sigmoid -> FP32 out [NB,1,256,256]
__global__ void final_k(const bf* __restrict__ in, const float* __restrict__ wT,
                        const float* __restrict__ b, float* __restrict__ out) {
    __shared__ float sw[480];
    __shared__ float sb[16];
    {
        const float4* s4 = (const float4*)wT;
        float4* d4 = (float4*)sw;
        if (threadIdx.x < 120) d4[threadIdx.x] = s4[threadIdx.x];
        if (threadIdx.x < 16) sb[threadIdx.x] = b[threadIdx.x];
    }
    __syncthreads();
    int t = blockIdx.x*256 + threadIdx.x;
    int wcol = t & 63, h = (t >> 6) & 63, n = t >> 12;
    float acc[16];
    #pragma unroll
    for (int o = 0; o < 16; ++o) acc[o] = sb[o];
    for (int c = 0; c < 30; ++c) {
        float v = B2F(in[((size_t)n*30 + c)*4096 + h*64 + wcol]);
        const float4* wp = (const float4*)(sw + c*16);
        #pragma unroll
        for (int q = 0; q < 4; ++q) {
            float4 wv = wp[q];
            acc[q*4+0] = fmaf(v, wv.x, acc[q*4+0]);
            acc[q*4+1] = fmaf(v, wv.y, acc[q*4+1]);
            acc[q*4+2] = fmaf(v, wv.z, acc[q*4+2]);
            acc[q*4+3] = fmaf(v, wv.w, acc[q*4+3]);
        }
    }
    size_t ob = (size_t)n*65536;
    #pragma unroll
    for (int i = 0; i < 4; ++i) {
        float4 sv;
        float* sp = (float*)&sv;
        #pragma unroll
        for (int j = 0; j < 4; ++j) {
            float xv = fmaxf(acc[i*4+j], 0.f);
            sp[j] = 1.f / (1.f + __expf(-xv));
        }
        *(float4*)(out + ob + (size_t)(h*4+i)*256 + wcol*4) = sv;
    }
}

extern "C" void kernel_launch(void* const* d_in, const int* in_sizes, int n_in,
                              void* d_out, int out_size, void* d_ws, size_t ws_size,
                              hipStream_t stream) {
    (void)in_sizes; (void)n_in; (void)out_size;
    const float* x   = (const float*)d_in[0];
    const float* c1w = (const float*)d_in[1];  const float* c1b = (const float*)d_in[2];
    const float* c2w = (const float*)d_in[3];  const float* c2b = (const float*)d_in[4];
    const float* c3w = (const float*)d_in[5];  const float* c3b = (const float*)d_in[6];
    const float* c4w = (const float*)d_in[7];  const float* c4b = (const float*)d_in[8];
    const float* c5w = (const float*)d_in[9];  const float* c5b = (const float*)d_in[10];
    const float* c6w = (const float*)d_in[11]; const float* c6b = (const float*)d_in[12];
    const float* c7w = (const float*)d_in[13]; const float* c7b = (const float*)d_in[14];
    const float* r1w = (const float*)d_in[15]; const float* r1b = (const float*)d_in[16];
    const float* g1  = (const float*)d_in[17]; const float* be1 = (const float*)d_in[18];
    const float* r2w = (const float*)d_in[19]; const float* r2b = (const float*)d_in[20];
    const float* g2  = (const float*)d_in[21]; const float* be2 = (const float*)d_in[22];
    const float* pw  = (const float*)d_in[23]; const float* pb  = (const float*)d_in[24];
    const float* u1w = (const float*)d_in[25]; const float* u1b = (const float*)d_in[26];
    const float* u2w = (const float*)d_in[27]; const float* u2b = (const float*)d_in[28];
    float* out = (float*)d_out;

    char* base = (char*)d_ws;
    size_t cur = 0;
    auto alloc = [&](size_t bytes) -> char* {
        char* p = base + cur;
        cur = (cur + bytes + 255) & ~((size_t)255);
        return p;
    };
    bf* ds_bf   = (bf*)alloc(33554432);   // [128,32,64,64] bf16
    char* A     = alloc(67108864);        // region A: t1 -> r1raw -> (ybuf, u1out)
    bf* t1_bf   = (bf*)A;
    bf* r1raw   = (bf*)A;
    bf* ybuf    = (bf*)A;
    bf* u1out   = (bf*)(A + 33554432);
    bf* r2raw   = (bf*)alloc(20971520);
    float* t3   = (float*)alloc(2097152);
    float* t4   = (float*)alloc(2621440);
    float* t5   = (float*)alloc(983040);
    float* t6   = (float*)alloc(65536);
    float* blur = (float*)alloc(8192);
    float* bb   = (float*)alloc(294912);
    float* pwb  = (float*)alloc(10240);
    float* stats  = (float*)alloc(672);
    float* stats2 = stats + 128;
    float* ab1  = (float*)alloc(512);
    float* ab2  = (float*)alloc(160);
    float* wTc1 = (float*)alloc(288);
    float* wTc2 = (float*)alloc(25600);
    float* wTc3 = (float*)alloc(4608);
    float* wTr1 = (float*)alloc(110592);
    float* wTr2 = (float*)alloc(46080);
    float* wTu1 = (float*)alloc(21600);
    float* wTu2 = (float*)alloc(1920);
    float* pwT  = (float*)alloc(3840);

    if (ws_size < cur) return;

    hipMemsetAsync(stats, 0, 672, stream);

    auto tr = [&](const float* s, float* d, int O, int CK) {
        int n = O*CK;
        transpose_w<<<(n + 255)/256, 256, 0, stream>>>(s, d, O, CK);
    };
    tr(c1w, wTc1, 8, 9);
    tr(c2w, wTc2, 32, 200);
    tr(c3w, wTc3, 4, 288);
    tr(r1w, wTr1, 64, 432);
    tr(r2w, wTr2, 20, 576);
    tr(u1w, wTu1, 30, 180);
    tr(u2w, wTu2, 16, 30);
    tr(pw,  pwT,  20, 48);

    conv1_k<<<2048, 256, 0, stream>>>(x, wTc1, c1b, t1_bf);
    conv2_k<<<1024, 256, 0, stream>>>(t1_bf, wTc2, c2b, ds_bf);
    conv3_k<<<512, 256, 0, stream>>>(ds_bf, wTc3, c3b, t3);
    conv4_k<<<2560, 256, 0, stream>>>(t3, c4w, c4b, t4);
    conv5_k<<<960, 256, 0, stream>>>(t4, c5w, c5b, t5);
    conv6_k<<<64, 256, 0, stream>>>(t5, c6w, c6b, t6);
    conv7_k<<<8, 256, 0, stream>>>(t6, c7w, c7b, blur);
    biasblur_k<<<288, 256, 0, stream>>>(blur, r1w, bb);
    r1conv_k<<<2048, 256, 0, stream>>>(ds_bf, bb, r1b, wTr1, r1raw);
    stats_k<64, 32><<<2048, 256, 0, stream>>>(r1raw, stats);
    fstats_k<<<1, 64, 0, stream>>>(stats, g1, be1, ab1, 64);
    r2conv_k<<<512, 256, 0, stream>>>(r1raw, ab1, r2b, wTr2, r2raw);
    stats_k<20, 32><<<640, 256, 0, stream>>>(r2raw, stats2);
    fstats_k<<<1, 32, 0, stream>>>(stats2, g2, be2, ab2, 20);
    pwbias_k<<<10, 256, 0, stream>>>(blur, pw, pb, pwb);
    finalize2_k<<<2048, 256, 0, stream>>>(r2raw, ab2, ds_bf, pwT, pwb, ybuf);
    u1conv_k<<<1024, 256, 0, stream>>>(ybuf, u1b, wTu1, u1out);
    final_k<<<2048, 256, 0, stream>>>(u1out, wTu2, u2b, out);
}

// Round 10
// 873.291 us; speedup vs baseline: 2.3984x; 2.0849x over previous
//
#include <hip/hip_runtime.h>
#include <hip/hip_bf16.h>

#define NB 128
typedef __hip_bfloat16 bf;
typedef short short8 __attribute__((ext_vector_type(8)));
typedef float f32x4 __attribute__((ext_vector_type(4)));

__device__ __forceinline__ float relu_(float x){ return fmaxf(x, 0.f); }
__device__ __forceinline__ float B2F(bf v){ return __bfloat162float(v); }
__device__ __forceinline__ bf F2B(float v){ return __float2bfloat16(v); }

// transpose w[O][CK] -> wT[CK][O]
__global__ void transpose_w(const float* __restrict__ src, float* __restrict__ dst, int O, int CK) {
    int t = blockIdx.x*blockDim.x + threadIdx.x;
    if (t >= O*CK) return;
    int o = t / CK, ck = t - o*CK;
    dst[ck*O + o] = src[t];
}

// pack conv weights fp32 [O][CIfull][3][3] (ci subrange) -> bf16 [Opad][9*CI], k = tap*CI + ci
__global__ void prep_wkb(const float* __restrict__ src, bf* __restrict__ dst,
                         int O, int CIfull, int ci_off, int CI, int total) {
    int t = blockIdx.x*256 + threadIdx.x;
    if (t >= total) return;
    int K = 9*CI;
    int o = t / K, k = t - o*K;
    int tap = k / CI, ci = k - tap*CI;
    float v = (o < O) ? src[((size_t)(o*CIfull + ci_off + ci))*9 + tap] : 0.f;
    dst[t] = F2B(v);
}

// conv1: x[NB,1,256,256] fp32 -> bf16 NCHW [NB,8,128,128], 3x3 s2 p1, relu
__global__ void conv1_k(const float* __restrict__ x, const float* __restrict__ wT,
                        const float* __restrict__ b, bf* __restrict__ out) {
    __shared__ float sw[72];
    __shared__ float sb[8];
    if (threadIdx.x < 72) sw[threadIdx.x] = wT[threadIdx.x];
    if (threadIdx.x < 8)  sb[threadIdx.x] = b[threadIdx.x];
    __syncthreads();
    int t = blockIdx.x*256 + threadIdx.x;
    int ow = t & 127, oh = (t >> 7) & 127, n = t >> 14;
    float acc[8];
    #pragma unroll
    for (int o = 0; o < 8; ++o) acc[o] = sb[o];
    const float* ip = x + (size_t)n * 65536;
    for (int kh = 0; kh < 3; ++kh) {
        int ih = oh*2 - 1 + kh;
        if ((unsigned)ih >= 256u) continue;
        for (int kw = 0; kw < 3; ++kw) {
            int iw = ow*2 - 1 + kw;
            if ((unsigned)iw >= 256u) continue;
            float v = ip[ih*256 + iw];
            const float4* wp = (const float4*)(sw + (kh*3+kw)*8);
            #pragma unroll
            for (int q = 0; q < 2; ++q) {
                float4 wv = wp[q];
                acc[q*4+0] = fmaf(v, wv.x, acc[q*4+0]);
                acc[q*4+1] = fmaf(v, wv.y, acc[q*4+1]);
                acc[q*4+2] = fmaf(v, wv.z, acc[q*4+2]);
                acc[q*4+3] = fmaf(v, wv.w, acc[q*4+3]);
            }
        }
    }
    size_t base = (size_t)n*131072 + (size_t)oh*128 + ow;
    #pragma unroll
    for (int o = 0; o < 8; ++o) out[base + (size_t)o*16384] = F2B(relu_(acc[o]));
}

// conv2: bf16 NCHW [NB,8,128,128] -> bf16 NHWC ds[NB,64,64,32], 5x5 s2 p2, relu
__global__ void conv2_k(const bf* __restrict__ in, const float* __restrict__ wT,
                        const float* __restrict__ b, bf* __restrict__ out) {
    __shared__ float sw[6400];
    __shared__ float sb[32];
    {
        const float4* s4 = (const float4*)wT;
        float4* d4 = (float4*)sw;
        for (int i = threadIdx.x; i < 1600; i += 256) d4[i] = s4[i];
        if (threadIdx.x < 32) sb[threadIdx.x] = b[threadIdx.x];
    }
    __syncthreads();
    int t = blockIdx.x*256 + threadIdx.x;
    int ow = t & 63, oh = (t >> 6) & 63, n = t >> 12;
    float acc[32];
    #pragma unroll
    for (int o = 0; o < 32; ++o) acc[o] = sb[o];
    for (int c = 0; c < 8; ++c) {
        const bf* ip = in + ((size_t)n*8 + c)*16384;
        for (int kh = 0; kh < 5; ++kh) {
            int ih = oh*2 - 2 + kh;
            if ((unsigned)ih >= 128u) continue;
            for (int kw = 0; kw < 5; ++kw) {
                int iw = ow*2 - 2 + kw;
                if ((unsigned)iw >= 128u) continue;
                float v = B2F(ip[ih*128 + iw]);
                const float4* wp = (const float4*)(sw + ((c*5+kh)*5+kw)*32);
                #pragma unroll
                for (int q = 0; q < 8; ++q) {
                    float4 wv = wp[q];
                    acc[q*4+0] = fmaf(v, wv.x, acc[q*4+0]);
                    acc[q*4+1] = fmaf(v, wv.y, acc[q*4+1]);
                    acc[q*4+2] = fmaf(v, wv.z, acc[q*4+2]);
                    acc[q*4+3] = fmaf(v, wv.w, acc[q*4+3]);
                }
            }
        }
    }
    size_t base = (((size_t)n*64 + oh)*64 + ow)*32;   // NHWC
    bf tmp[32];
    #pragma unroll
    for (int o = 0; o < 32; ++o) tmp[o] = F2B(relu_(acc[o]));
    #pragma unroll
    for (int q = 0; q < 4; ++q) *(uint4*)(out + base + q*8) = ((uint4*)tmp)[q];
}

// conv3: NHWC ds[NB,64,64,32] -> fp32 NCHW [NB,4,32,32], 3x3 s2 p1, NO relu
__global__ void conv3_k(const bf* __restrict__ in, const float* __restrict__ wT,
                        const float* __restrict__ b, float* __restrict__ out) {
    __shared__ float sw[1152];
    __shared__ float sb[4];
    {
        const float4* s4 = (const float4*)wT;
        float4* d4 = (float4*)sw;
        for (int i = threadIdx.x; i < 288; i += 256) d4[i] = s4[i];
        if (threadIdx.x < 4) sb[threadIdx.x] = b[threadIdx.x];
    }
    __syncthreads();
    int t = blockIdx.x*256 + threadIdx.x;
    int ow = t & 31, oh = (t >> 5) & 31, n = t >> 10;
    float acc[4];
    #pragma unroll
    for (int o = 0; o < 4; ++o) acc[o] = sb[o];
    for (int kh = 0; kh < 3; ++kh) {
        int ih = oh*2 - 1 + kh;
        if ((unsigned)ih >= 64u) continue;
        for (int kw = 0; kw < 3; ++kw) {
            int iw = ow*2 - 1 + kw;
            if ((unsigned)iw >= 64u) continue;
            const bf* basep = in + (((size_t)(n*64 + ih))*64 + iw)*32;
            #pragma unroll
            for (int c8 = 0; c8 < 4; ++c8) {
                uint4 r = *(const uint4*)(basep + c8*8);
                const bf* pv = (const bf*)&r;
                #pragma unroll
                for (int j = 0; j < 8; ++j) {
                    float v = B2F(pv[j]);
                    int c = c8*8 + j;
                    const float4 wv = *(const float4*)(sw + (c*9 + kh*3 + kw)*4);
                    acc[0] = fmaf(v, wv.x, acc[0]);
                    acc[1] = fmaf(v, wv.y, acc[1]);
                    acc[2] = fmaf(v, wv.z, acc[2]);
                    acc[3] = fmaf(v, wv.w, acc[3]);
                }
            }
        }
    }
    size_t base = (size_t)n*4096 + (size_t)oh*32 + ow;
    #pragma unroll
    for (int o = 0; o < 4; ++o) out[base + (size_t)o*1024] = acc[o];
}

// conv4: fp32 [NB,4,32,32] -> fp32 [NB,20,16,16], 3x3 s2 p1, relu
__global__ void conv4_k(const float* __restrict__ in, const float* __restrict__ w,
                        const float* __restrict__ b, float* __restrict__ out) {
    int o = blockIdx.x % 20, n = blockIdx.x / 20;
    int hw = threadIdx.x, ow = hw & 15, oh = hw >> 4;
    float acc = b[o];
    for (int c = 0; c < 4; ++c) {
        const float* ip = in + ((size_t)n*4 + c)*1024;
        const float* wp = w + (o*4 + c)*9;
        for (int kh = 0; kh < 3; ++kh) {
            int ih = oh*2 - 1 + kh;
            if ((unsigned)ih >= 32u) continue;
            for (int kw = 0; kw < 3; ++kw) {
                int iw = ow*2 - 1 + kw;
                if ((unsigned)iw >= 32u) continue;
                acc = fmaf(ip[ih*32 + iw], wp[kh*3+kw], acc);
            }
        }
    }
    out[((size_t)n*20 + o)*256 + hw] = relu_(acc);
}

// conv5: [NB,20,16,16] -> [NB,30,8,8], 5x5 s2 p2, relu
__global__ void conv5_k(const float* __restrict__ in, const float* __restrict__ w,
                        const float* __restrict__ b, float* __restrict__ out) {
    int t = blockIdx.x*256 + threadIdx.x;
    int lane = t & 63, wid = t >> 6;
    int o = wid % 30, n = wid / 30;
    int ow = lane & 7, oh = lane >> 3;
    float acc = b[o];
    for (int c = 0; c < 20; ++c) {
        const float* ip = in + ((size_t)n*20 + c)*256;
        const float* wp = w + (o*20 + c)*25;
        for (int kh = 0; kh < 5; ++kh) {
            int ih = oh*2 - 2 + kh;
            if ((unsigned)ih >= 16u) continue;
            for (int kw = 0; kw < 5; ++kw) {
                int iw = ow*2 - 2 + kw;
                if ((unsigned)iw >= 16u) continue;
                acc = fmaf(ip[ih*16 + iw], wp[kh*5+kw], acc);
            }
        }
    }
    out[((size_t)n*30 + o)*64 + lane] = relu_(acc);
}

// conv6: [NB,30,8,8] -> [NB,8,4,4], 3x3 s2 p1, relu
__global__ void conv6_k(const float* __restrict__ in, const float* __restrict__ w,
                        const float* __restrict__ b, float* __restrict__ out) {
    int t = blockIdx.x*256 + threadIdx.x;
    int hw = t & 15, o = (t >> 4) & 7, n = t >> 7;
    int ow = hw & 3, oh = hw >> 2;
    float acc = b[o];
    for (int c = 0; c < 30; ++c) {
        const float* ip = in + ((size_t)n*30 + c)*64;
        const float* wp = w + (o*30 + c)*9;
        for (int kh = 0; kh < 3; ++kh) {
            int ih = oh*2 - 1 + kh;
            if ((unsigned)ih >= 8u) continue;
            for (int kw = 0; kw < 3; ++kw) {
                int iw = ow*2 - 1 + kw;
                if ((unsigned)iw >= 8u) continue;
                acc = fmaf(ip[ih*8 + iw], wp[kh*3+kw], acc);
            }
        }
    }
    out[((size_t)n*8 + o)*16 + hw] = relu_(acc);
}

// conv7: [NB,8,4,4] -> blur[NB,16]
__global__ void conv7_k(const float* __restrict__ in, const float* __restrict__ w,
                        const float* __restrict__ b, float* __restrict__ blur) {
    int t = blockIdx.x*256 + threadIdx.x;
    int pos = t & 15, n = t >> 4;
    float acc = b[0];
    for (int c = 0; c < 8; ++c) acc = fmaf(in[((size_t)n*8 + c)*16 + pos], w[c], acc);
    blur[n*16 + pos] = relu_(acc);
}

// blur channels of r1-conv are spatially constant -> per-(n, border-class, o) bias
__global__ void biasblur_k(const float* __restrict__ blur, const float* __restrict__ w1,
                           float* __restrict__ bb) {
    int t = blockIdx.x*256 + threadIdx.x;   // 128*9*64
    int o = t & 63, cls = (t >> 6) % 9, n = t / 576;
    int hc = cls / 3, wc = cls % 3;
    int kh0 = (hc == 0) ? 1 : 0, kh1 = (hc == 2) ? 1 : 2;
    int kw0 = (wc == 0) ? 1 : 0, kw1 = (wc == 2) ? 1 : 2;
    float s = 0.f;
    for (int c = 0; c < 16; ++c) {
        float bv = blur[n*16 + c];
        float ws = 0.f;
        for (int kh = kh0; kh <= kh1; ++kh)
            for (int kw = kw0; kw <= kw1; ++kw)
                ws += w1[((o*48 + c)*3 + kh)*3 + kw];
        s = fmaf(bv, ws, s);
    }
    bb[((size_t)n*9 + cls)*64 + o] = s;
}

// r1 MFMA: NHWC ds[NB,64,64,32] -> NHWC r1raw[NB,64,64,64]; 3x3 s1 p1; +bias+blur-bias
// block = (n, 4 rows); wave = 1 row, 4 M-subtiles x 4 N-tiles; K = 9 taps x 32 ci
__global__ __launch_bounds__(256, 4) void r1mfma_k(const bf* __restrict__ in, const bf* __restrict__ wkb,
                        const float* __restrict__ r1b, const float* __restrict__ bb,
                        bf* __restrict__ out) {
    __shared__ bf bfr[2304*8];     // 36 KB: frag f = (ks*4+nt)*64 + lane
    __shared__ float bbs[576];     // 9 cls x 64 oc combined bias
    int n = blockIdx.x >> 4, oh4 = blockIdx.x & 15;
    for (int f = threadIdx.x; f < 2304; f += 256) {
        int fl = f & 63, nt = (f >> 6) & 3, ks = f >> 8;
        const bf* s = wkb + (size_t)(nt*16 + (fl & 15))*288 + ks*32 + (fl >> 4)*8;
        *(uint4*)(bfr + f*8) = *(const uint4*)s;
    }
    for (int i = threadIdx.x; i < 576; i += 256) {
        bbs[i] = r1b[i & 63] + bb[(size_t)n*576 + i];
    }
    __syncthreads();
    int wave = threadIdx.x >> 6, lane = threadIdx.x & 63;
    int l15 = lane & 15, lk = lane >> 4;
    int oh = oh4*4 + wave;
    f32x4 acc[4][4];
    #pragma unroll
    for (int s = 0; s < 4; ++s)
        #pragma unroll
        for (int t = 0; t < 4; ++t) { acc[s][t][0]=0.f; acc[s][t][1]=0.f; acc[s][t][2]=0.f; acc[s][t][3]=0.f; }
    const short8 zero8 = {0,0,0,0,0,0,0,0};
    #pragma unroll
    for (int ks = 0; ks < 9; ++ks) {
        int kh = ks / 3, kw = ks - kh*3;
        int ih = oh + kh - 1;
        bool vh = (unsigned)ih < 64u;
        int ihc = vh ? ih : 0;
        const bf* rowb = in + (((size_t)n*64 + ihc)*64)*32 + lk*8;
        short8 afr[4];
        #pragma unroll
        for (int s = 0; s < 4; ++s) {
            int iw = s*16 + l15 + kw - 1;
            bool vw = vh && ((unsigned)iw < 64u);
            int iwc = (iw < 0) ? 0 : ((iw > 63) ? 63 : iw);
            short8 ld = *(const short8*)(rowb + iwc*32);
            afr[s] = vw ? ld : zero8;
        }
        #pragma unroll
        for (int nt = 0; nt < 4; ++nt) {
            short8 bfrg = *(const short8*)(bfr + ((ks*4 + nt)*64 + lane)*8);
            #pragma unroll
            for (int s = 0; s < 4; ++s)
                acc[s][nt] = __builtin_amdgcn_mfma_f32_16x16x32_bf16(afr[s], bfrg, acc[s][nt], 0, 0, 0);
        }
    }
    int hc = (oh == 0) ? 0 : ((oh == 63) ? 2 : 1);
    size_t outrow = ((size_t)n*64 + oh)*64;
    #pragma unroll
    for (int s = 0; s < 4; ++s) {
        int ow0 = s*16 + lk*4;
        #pragma unroll
        for (int r = 0; r < 4; ++r) {
            int ow = ow0 + r;
            int wc = (ow == 0) ? 0 : ((ow == 63) ? 2 : 1);
            const float* bp = bbs + (hc*3 + wc)*64;
            #pragma unroll
            for (int nt = 0; nt < 4; ++nt) {
                int oc = nt*16 + l15;
                out[(outrow + ow)*64 + oc] = F2B(acc[s][nt][r] + bp[oc]);
            }
        }
    }
}

// per-channel sum/sumsq over NHWC r1raw [M=NB*4096][64]
__global__ void stats64n_k(const bf* __restrict__ x, float* __restrict__ sums) {
    int c = threadIdx.x & 63, g = threadIdx.x >> 6;
    float s = 0.f, sq = 0.f;
    int m0 = blockIdx.x*1024;
    for (int i = 0; i < 256; ++i) {
        int m = m0 + i*4 + g;
        float v = B2F(x[(size_t)m*64 + c]);
        s += v; sq = fmaf(v, v, sq);
    }
    __shared__ float ls[256], lq[256];
    ls[threadIdx.x] = s; lq[threadIdx.x] = sq;
    __syncthreads();
    if (threadIdx.x < 64) {
        float S = ls[threadIdx.x] + ls[64+threadIdx.x] + ls[128+threadIdx.x] + ls[192+threadIdx.x];
        float Q = lq[threadIdx.x] + lq[64+threadIdx.x] + lq[128+threadIdx.x] + lq[192+threadIdx.x];
        atomicAdd(&sums[threadIdx.x*2],   S);
        atomicAdd(&sums[threadIdx.x*2+1], Q);
    }
}

// fold BN into per-channel a*x + b
__global__ void fstats_k(const float* __restrict__ sums, const float* __restrict__ g,
                         const float* __restrict__ be, float* __restrict__ ab, int C) {
    int c = blockIdx.x*blockDim.x + threadIdx.x;
    if (c >= C) return;
    const float inv = 1.f / (float)(NB*4096);
    float mean = sums[c*2] * inv;
    float var  = sums[c*2+1] * inv - mean*mean;
    float a = g[c] * rsqrtf(var + 1e-5f);
    ab[c*2] = a;
    ab[c*2+1] = be[c] - mean*a;
}

// in-place bn+relu on NHWC r1raw (64 ch)
__global__ void bnact_k(bf* __restrict__ x, const float* __restrict__ ab) {
    __shared__ float sab[128];
    if (threadIdx.x < 128) sab[threadIdx.x] = ab[threadIdx.x];
    __syncthreads();
    int t = blockIdx.x*256 + threadIdx.x;
    size_t base = (size_t)t*8;
    int c0 = (t << 3) & 63;
    uint4 r = *(const uint4*)(x + base);
    const bf* pv = (const bf*)&r;
    bf o[8];
    #pragma unroll
    for (int j = 0; j < 8; ++j) {
        float v = fmaf(B2F(pv[j]), sab[(c0+j)*2], sab[(c0+j)*2+1]);
        o[j] = F2B(fmaxf(v, 0.f));
    }
    *(uint4*)(x + base) = *(uint4*)o;
}

// r2 MFMA: NHWC r1act[NB,64,64,64] -> NCHW r2raw[NB,20,64,64]; 3x3 s1 p1
__global__ __launch_bounds__(256, 4) void r2mfma_k(const bf* __restrict__ in, const bf* __restrict__ wkb,
                        const float* __restrict__ r2b, bf* __restrict__ out) {
    __shared__ bf bfr[2304*8];   // 36 KB: frag f = (ks*2+nt)*64 + lane
    __shared__ float sb2[32];
    int n = blockIdx.x >> 4, oh4 = blockIdx.x & 15;
    for (int f = threadIdx.x; f < 2304; f += 256) {
        int fl = f & 63, nt = (f >> 6) & 1, ks = f >> 7;
        const bf* s = wkb + (size_t)(nt*16 + (fl & 15))*576 + ks*32 + (fl >> 4)*8;
        *(uint4*)(bfr + f*8) = *(const uint4*)s;
    }
    if (threadIdx.x < 32) sb2[threadIdx.x] = (threadIdx.x < 20) ? r2b[threadIdx.x] : 0.f;
    __syncthreads();
    int wave = threadIdx.x >> 6, lane = threadIdx.x & 63;
    int l15 = lane & 15, lk = lane >> 4;
    int oh = oh4*4 + wave;
    f32x4 acc[4][2];
    #pragma unroll
    for (int s = 0; s < 4; ++s)
        #pragma unroll
        for (int t = 0; t < 2; ++t) { acc[s][t][0]=0.f; acc[s][t][1]=0.f; acc[s][t][2]=0.f; acc[s][t][3]=0.f; }
    const short8 zero8 = {0,0,0,0,0,0,0,0};
    #pragma unroll
    for (int ks = 0; ks < 18; ++ks) {
        int tap = ks >> 1, kh = tap / 3, kw = tap - kh*3;
        int ci0 = (ks & 1)*32;
        int ih = oh + kh - 1;
        bool vh = (unsigned)ih < 64u;
        int ihc = vh ? ih : 0;
        const bf* rowb = in + (((size_t)n*64 + ihc)*64)*64 + ci0 + lk*8;
        short8 afr[4];
        #pragma unroll
        for (int s = 0; s < 4; ++s) {
            int iw = s*16 + l15 + kw - 1;
            bool vw = vh && ((unsigned)iw < 64u);
            int iwc = (iw < 0) ? 0 : ((iw > 63) ? 63 : iw);
            short8 ld = *(const short8*)(rowb + (size_t)iwc*64);
            afr[s] = vw ? ld : zero8;
        }
        #pragma unroll
        for (int nt = 0; nt < 2; ++nt) {
            short8 bfrg = *(const short8*)(bfr + ((ks*2 + nt)*64 + lane)*8);
            #pragma unroll
            for (int s = 0; s < 4; ++s)
                acc[s][nt] = __builtin_amdgcn_mfma_f32_16x16x32_bf16(afr[s], bfrg, acc[s][nt], 0, 0, 0);
        }
    }
    size_t hwrow = (size_t)oh*64;
    #pragma unroll
    for (int nt = 0; nt < 2; ++nt) {
        int oc = nt*16 + l15;
        if (oc < 20) {
            float bv = sb2[oc];
            bf* op = out + ((size_t)n*20 + oc)*4096 + hwrow;
            #pragma unroll
            for (int s = 0; s < 4; ++s) {
                int ow0 = s*16 + lk*4;
                #pragma unroll
                for (int r = 0; r < 4; ++r)
                    op[ow0 + r] = F2B(acc[s][nt][r] + bv);
            }
        }
    }
}

// per-channel sum/sumsq over bf16 NCHW [NB,C,64,64]
template<int C, int BPC>
__global__ void stats_k(const bf* __restrict__ x, float* __restrict__ sums) {
    int c = blockIdx.x / BPC, bk = blockIdx.x % BPC;
    float s = 0.f, sq = 0.f;
    const int M = NB*4096;
    for (int i = bk*256 + threadIdx.x; i < M; i += BPC*256) {
        int n = i >> 12, r = i & 4095;
        float v = B2F(x[(((size_t)n*C + c) << 12) + r]);
        s += v; sq = fmaf(v, v, sq);
    }
    __shared__ float ls[256], lq[256];
    ls[threadIdx.x] = s; lq[threadIdx.x] = sq;
    __syncthreads();
    for (int st = 128; st > 0; st >>= 1) {
        if (threadIdx.x < st) { ls[threadIdx.x] += ls[threadIdx.x+st]; lq[threadIdx.x] += lq[threadIdx.x+st]; }
        __syncthreads();
    }
    if (threadIdx.x == 0) {
        atomicAdd(&sums[c*2], ls[0]);
        atomicAdd(&sums[c*2+1], lq[0]);
    }
}

// blur part of pointwise conv -> per-(n,o) scalar
__global__ void pwbias_k(const float* __restrict__ blur, const float* __restrict__ pw,
                         const float* __restrict__ pb, float* __restrict__ out) {
    int t = blockIdx.x*256 + threadIdx.x;
    if (t >= NB*20) return;
    int o = t % 20, n = t / 20;
    float s = pb[o];
    for (int c = 0; c < 16; ++c) s = fmaf(blur[n*16 + c], pw[o*48 + c], s);
    out[n*20 + o] = s;
}

// y = bn2(r2raw NCHW) + pw conv (NHWC ds) + pwb
__global__ void finalize2_k(const bf* __restrict__ r2raw, const float* __restrict__ ab2,
                            const bf* __restrict__ ds, const float* __restrict__ pwT,
                            const float* __restrict__ pwb, bf* __restrict__ out) {
    __shared__ float sw[960];
    __shared__ float sab[40];
    {
        const float4* s4 = (const float4*)pwT;
        float4* d4 = (float4*)sw;
        if (threadIdx.x < 240) d4[threadIdx.x] = s4[threadIdx.x];
        if (threadIdx.x < 40) sab[threadIdx.x] = ab2[threadIdx.x];
    }
    __syncthreads();
    int t = blockIdx.x*256 + threadIdx.x;
    int hw = t & 4095, n = t >> 12;
    float acc[20];
    const float* pwbp = pwb + n*20;
    #pragma unroll
    for (int o = 0; o < 20; ++o) acc[o] = pwbp[o];
    const bf* dsp = ds + ((size_t)(n*4096) + hw)*32;
    #pragma unroll
    for (int c8 = 0; c8 < 4; ++c8) {
        uint4 rr = *(const uint4*)(dsp + c8*8);
        const bf* pv = (const bf*)&rr;
        #pragma unroll
        for (int j = 0; j < 8; ++j) {
            float v = B2F(pv[j]);
            int c = c8*8 + j;
            const float4* wp = (const float4*)(sw + (16 + c)*20);
            #pragma unroll
            for (int q = 0; q < 5; ++q) {
                float4 wv = wp[q];
                acc[q*4+0] = fmaf(v, wv.x, acc[q*4+0]);
                acc[q*4+1] = fmaf(v, wv.y, acc[q*4+1]);
                acc[q*4+2] = fmaf(v, wv.z, acc[q*4+2]);
                acc[q*4+3] = fmaf(v, wv.w, acc[q*4+3]);
            }
        }
    }
    #pragma unroll
    for (int o = 0; o < 20; ++o) {
        size_t idx = ((size_t)n*20 + o)*4096 + hw;
        out[idx] = F2B(fmaf(B2F(r2raw[idx]), sab[o*2], sab[o*2+1]) + acc[o]);
    }
}

// u1: 3x3 conv 20->30 NCHW, relu
__global__ void __launch_bounds__(256) u1conv_k(const bf* __restrict__ in, const float* __restrict__ bias,
                         const float* __restrict__ wT, bf* __restrict__ out) {
    __shared__ float sw[5400];
    __shared__ float sb[30];
    {
        const float4* s4 = (const float4*)wT;
        float4* d4 = (float4*)sw;
        for (int i = threadIdx.x; i < 1350; i += 256) d4[i] = s4[i];
        if (threadIdx.x < 30) sb[threadIdx.x] = bias[threadIdx.x];
    }
    __syncthreads();
    int t = blockIdx.x*256 + threadIdx.x;
    int ow = t & 63, oh = (t >> 6) & 63, n = t >> 12;
    float acc[30];
    #pragma unroll
    for (int o = 0; o < 30; ++o) acc[o] = sb[o];
    for (int c = 0; c < 20; ++c) {
        const bf* ip = in + ((size_t)n*20 + c)*4096;
        for (int kh = 0; kh < 3; ++kh) {
            int ih = oh - 1 + kh;
            if ((unsigned)ih >= 64u) continue;
            for (int kw = 0; kw < 3; ++kw) {
                int iw = ow - 1 + kw;
                if ((unsigned)iw >= 64u) continue;
                float v = B2F(ip[ih*64 + iw]);
                const float2* wp = (const float2*)(sw + ((c*3+kh)*3+kw)*30);
                #pragma unroll
                for (int q = 0; q < 15; ++q) {
                    float2 wv = wp[q];
                    acc[q*2+0] = fmaf(v, wv.x, acc[q*2+0]);
                    acc[q*2+1] = fmaf(v, wv.y, acc[q*2+1]);
                }
            }
        }
    }
    size_t base = (size_t)n*122880 + (size_t)oh*64 + ow;
    #pragma unroll
    for (int o = 0; o < 30; ++o) out[base + (size_t)o*4096] = F2B(relu_(acc[o]));
}

// u2 1x1 (30->16) + relu + pixel_shuffle(4) + sigmoid -> FP32 out [NB,1,256,256]
__global__ void final_k(const bf* __restrict__ in, const float* __restrict__ wT,
                        const float* __restrict__ b, float* __restrict__ out) {
    __shared__ float sw[480];
    __shared__ float sb[16];
    {
        const float4* s4 = (const float4*)wT;
        float4* d4 = (float4*)sw;
        if (threadIdx.x < 120) d4[threadIdx.x] = s4[threadIdx.x];
        if (threadIdx.x < 16) sb[threadIdx.x] = b[threadIdx.x];
    }
    __syncthreads();
    int t = blockIdx.x*256 + threadIdx.x;
    int wcol = t & 63, h = (t >> 6) & 63, n = t >> 12;
    float acc[16];
    #pragma unroll
    for (int o = 0; o < 16; ++o) acc[o] = sb[o];
    for (int c = 0; c < 30; ++c) {
        float v = B2F(in[((size_t)n*30 + c)*4096 + h*64 + wcol]);
        const float4* wp = (const float4*)(sw + c*16);
        #pragma unroll
        for (int q = 0; q < 4; ++q) {
            float4 wv = wp[q];
            acc[q*4+0] = fmaf(v, wv.x, acc[q*4+0]);
            acc[q*4+1] = fmaf(v, wv.y, acc[q*4+1]);
            acc[q*4+2] = fmaf(v, wv.z, acc[q*4+2]);
            acc[q*4+3] = fmaf(v, wv.w, acc[q*4+3]);
        }
    }
    size_t ob = (size_t)n*65536;
    #pragma unroll
    for (int i = 0; i < 4; ++i) {
        float4 sv;
        float* sp = (float*)&sv;
        #pragma unroll
        for (int j = 0; j < 4; ++j) {
            float xv = fmaxf(acc[i*4+j], 0.f);
            sp[j] = 1.f / (1.f + __expf(-xv));
        }
        *(float4*)(out + ob + (size_t)(h*4+i)*256 + wcol*4) = sv;
    }
}

extern "C" void kernel_launch(void* const* d_in, const int* in_sizes, int n_in,
                              void* d_out, int out_size, void* d_ws, size_t ws_size,
                              hipStream_t stream) {
    (void)in_sizes; (void)n_in; (void)out_size;
    const float* x   = (const float*)d_in[0];
    const float* c1w = (const float*)d_in[1];  const float* c1b = (const float*)d_in[2];
    const float* c2w = (const float*)d_in[3];  const float* c2b = (const float*)d_in[4];
    const float* c3w = (const float*)d_in[5];  const float* c3b = (const float*)d_in[6];
    const float* c4w = (const float*)d_in[7];  const float* c4b = (const float*)d_in[8];
    const float* c5w = (const float*)d_in[9];  const float* c5b = (const float*)d_in[10];
    const float* c6w = (const float*)d_in[11]; const float* c6b = (const float*)d_in[12];
    const float* c7w = (const float*)d_in[13]; const float* c7b = (const float*)d_in[14];
    const float* r1w = (const float*)d_in[15]; const float* r1b = (const float*)d_in[16];
    const float* g1  = (const float*)d_in[17]; const float* be1 = (const float*)d_in[18];
    const float* r2w = (const float*)d_in[19]; const float* r2b = (const float*)d_in[20];
    const float* g2  = (const float*)d_in[21]; const float* be2 = (const float*)d_in[22];
    const float* pw  = (const float*)d_in[23]; const float* pb  = (const float*)d_in[24];
    const float* u1w = (const float*)d_in[25]; const float* u1b = (const float*)d_in[26];
    const float* u2w = (const float*)d_in[27]; const float* u2b = (const float*)d_in[28];
    float* out = (float*)d_out;

    char* base = (char*)d_ws;
    size_t cur = 0;
    auto alloc = [&](size_t bytes) -> char* {
        char* p = base + cur;
        cur = (cur + bytes + 255) & ~((size_t)255);
        return p;
    };
    bf* ds_bf   = (bf*)alloc(33554432);   // NHWC [128,64,64,32]
    char* A     = alloc(67108864);        // region A: t1 -> r1raw/r1act -> (ybuf, u1out)
    bf* t1_bf   = (bf*)A;                 // NCHW [128,8,128,128]
    bf* r1raw   = (bf*)A;                 // NHWC [128,64,64,64]
    bf* ybuf    = (bf*)A;                 // NCHW [128,20,64,64]
    bf* u1out   = (bf*)(A + 33554432);    // NCHW [128,30,64,64]
    bf* r2raw   = (bf*)alloc(20971520);   // NCHW [128,20,64,64]
    float* t3   = (float*)alloc(2097152);
    float* t4   = (float*)alloc(2621440);
    float* t5   = (float*)alloc(983040);
    float* t6   = (float*)alloc(65536);
    float* blur = (float*)alloc(8192);
    float* bb   = (float*)alloc(294912);
    float* pwb  = (float*)alloc(10240);
    float* stats  = (float*)alloc(672);
    float* stats2 = stats + 128;
    float* ab1  = (float*)alloc(512);
    float* ab2  = (float*)alloc(160);
    float* wTc1 = (float*)alloc(288);
    float* wTc2 = (float*)alloc(25600);
    float* wTc3 = (float*)alloc(4608);
    float* wTu1 = (float*)alloc(21600);
    float* wTu2 = (float*)alloc(1920);
    float* pwT  = (float*)alloc(3840);
    bf* wkb1    = (bf*)alloc(36864);      // [64][288] bf16
    bf* wkb2    = (bf*)alloc(36864);      // [32][576] bf16 (rows 20..31 zero)

    if (ws_size < cur) return;

    hipMemsetAsync(stats, 0, 672, stream);

    auto tr = [&](const float* s, float* d, int O, int CK) {
        int n = O*CK;
        transpose_w<<<(n + 255)/256, 256, 0, stream>>>(s, d, O, CK);
    };
    tr(c1w, wTc1, 8, 9);
    tr(c2w, wTc2, 32, 200);
    tr(c3w, wTc3, 4, 288);
    tr(u1w, wTu1, 30, 180);
    tr(u2w, wTu2, 16, 30);
    tr(pw,  pwT,  20, 48);
    prep_wkb<<<72, 256, 0, stream>>>(r1w, wkb1, 64, 48, 16, 32, 18432);
    prep_wkb<<<72, 256, 0, stream>>>(r2w, wkb2, 20, 64, 0, 64, 18432);

    conv1_k<<<8192, 256, 0, stream>>>(x, wTc1, c1b, t1_bf);
    conv2_k<<<2048, 256, 0, stream>>>(t1_bf, wTc2, c2b, ds_bf);
    conv3_k<<<512, 256, 0, stream>>>(ds_bf, wTc3, c3b, t3);
    conv4_k<<<2560, 256, 0, stream>>>(t3, c4w, c4b, t4);
    conv5_k<<<960, 256, 0, stream>>>(t4, c5w, c5b, t5);
    conv6_k<<<64, 256, 0, stream>>>(t5, c6w, c6b, t6);
    conv7_k<<<8, 256, 0, stream>>>(t6, c7w, c7b, blur);
    biasblur_k<<<288, 256, 0, stream>>>(blur, r1w, bb);
    r1mfma_k<<<2048, 256, 0, stream>>>(ds_bf, wkb1, r1b, bb, r1raw);   // overwrites t1 (dead)
    stats64n_k<<<512, 256, 0, stream>>>(r1raw, stats);
    fstats_k<<<1, 64, 0, stream>>>(stats, g1, be1, ab1, 64);
    bnact_k<<<16384, 256, 0, stream>>>(r1raw, ab1);                    // in-place -> r1act
    r2mfma_k<<<2048, 256, 0, stream>>>(r1raw, wkb2, r2b, r2raw);
    stats_k<20, 32><<<640, 256, 0, stream>>>(r2raw, stats2);
    fstats_k<<<1, 32, 0, stream>>>(stats2, g2, be2, ab2, 20);
    pwbias_k<<<10, 256, 0, stream>>>(blur, pw, pb, pwb);
    finalize2_k<<<2048, 256, 0, stream>>>(r2raw, ab2, ds_bf, pwT, pwb, ybuf);  // overwrites r1act (dead)
    u1conv_k<<<2048, 256, 0, stream>>>(ybuf, u1b, wTu1, u1out);
    final_k<<<2048, 256, 0, stream>>>(u1out, wTu2, u2b, out);
}